// Round 3
// baseline (2579.800 us; speedup 1.0000x reference)
//
#include <hip/hip_runtime.h>
#include <math.h>

namespace {
constexpr int kB = 2;
constexpr int kT = 2048;
constexpr int kD = 1024;
constexpr int kH = 16;
constexpr int kL = 8;
constexpr int kInner = 4096;
constexpr int kM = kB * kT;  // 4096 token rows
constexpr float kEps = 1e-5f;
}

typedef __attribute__((ext_vector_type(8))) short bf16x8;
typedef __attribute__((ext_vector_type(4))) float f32x4;
typedef __attribute__((ext_vector_type(16))) float f32x16;

typedef const __attribute__((address_space(1))) void* gas_t;
typedef __attribute__((address_space(3))) void* las_t;

__device__ __forceinline__ short f2bf(float f) {
  union { float f; unsigned u; } v{f};
  unsigned r = (v.u + 0x7FFF + ((v.u >> 16) & 1)) >> 16;
  return (short)r;
}

__device__ __forceinline__ unsigned cvtpk_bf16(float lo, float hi) {
  unsigned r;
  asm("v_cvt_pk_bf16_f32 %0, %1, %2" : "=v"(r) : "v"(lo), "v"(hi));
  return r;
}

__device__ __forceinline__ void half_swap(unsigned& a, unsigned& b, bool ishi) {
  const unsigned sel = ishi ? a : b;
  const unsigned got = (unsigned)__shfl_xor((int)sel, 32, 64);
  a = ishi ? got : a;
  b = ishi ? b : got;
}

// ---------------- LayerNorm: one 256-thread block per row of 1024 ----------------
template <typename OT>
__global__ __launch_bounds__(256) void ln_kernel(
    const float* __restrict__ in, const float* __restrict__ w,
    const float* __restrict__ b, OT* __restrict__ out) {
  const int row = blockIdx.x;
  const int tid = threadIdx.x;
  const float4 v = ((const float4*)(in + (size_t)row * kD))[tid];
  float sum = v.x + v.y + v.z + v.w;
  float sq = v.x * v.x + v.y * v.y + v.z * v.z + v.w * v.w;
#pragma unroll
  for (int off = 32; off > 0; off >>= 1) {
    sum += __shfl_down(sum, off);
    sq += __shfl_down(sq, off);
  }
  __shared__ float s1[4], s2[4];
  const int wave = tid >> 6, lane = tid & 63;
  if (lane == 0) { s1[wave] = sum; s2[wave] = sq; }
  __syncthreads();
  const float ts = s1[0] + s1[1] + s1[2] + s1[3];
  const float tq = s2[0] + s2[1] + s2[2] + s2[3];
  const float mean = ts * (1.0f / kD);
  const float var = tq * (1.0f / kD) - mean * mean;
  const float rs = rsqrtf(var + kEps);
  const float4 w4 = ((const float4*)w)[tid];
  const float4 b4 = ((const float4*)b)[tid];
  float4 o;
  o.x = (v.x - mean) * rs * w4.x + b4.x;
  o.y = (v.y - mean) * rs * w4.y + b4.y;
  o.z = (v.z - mean) * rs * w4.z + b4.z;
  o.w = (v.w - mean) * rs * w4.w + b4.w;
  if constexpr (sizeof(OT) == 4) {
    ((float4*)(out + (size_t)row * kD))[tid] = o;
  } else {
    short4 s4;
    s4.x = f2bf(o.x); s4.y = f2bf(o.y); s4.z = f2bf(o.z); s4.w = f2bf(o.w);
    ((short4*)(out + (size_t)row * kD))[tid] = s4;
  }
}

// ------------- per-layer weight convert+transpose: fp32 [K,N] -> bf16 [N,K] -----
__global__ __launch_bounds__(256) void convT_kernel(
    const float* __restrict__ aw, const float* __restrict__ pw,
    const float* __restrict__ fw, const float* __restrict__ gw,
    short* __restrict__ awT, short* __restrict__ pwT,
    short* __restrict__ fwT, short* __restrict__ gwT) {
  __shared__ short t[64][66];
  int b = blockIdx.x;
  const float* src; short* dst; int K, N, tk, tn;
  if (b < 768)       { src = aw; dst = awT; K = 1024; N = 3072; tk = b / 48; tn = b % 48; }
  else if (b < 1024) { b -= 768;  src = pw; dst = pwT; K = 1024; N = 1024; tk = b / 16; tn = b % 16; }
  else if (b < 2048) { b -= 1024; src = fw; dst = fwT; K = 1024; N = 4096; tk = b / 64; tn = b % 64; }
  else               { b -= 2048; src = gw; dst = gwT; K = 4096; N = 1024; tk = b / 16; tn = b % 16; }
  const int k0 = tk * 64, n0 = tn * 64;
  const int tr = threadIdx.x >> 4, tc4 = (threadIdx.x & 15) << 2;
#pragma unroll
  for (int i = 0; i < 4; ++i) {
    const int k = tr + i * 16;
    const float4 v = *(const float4*)(src + (size_t)(k0 + k) * N + n0 + tc4);
    t[k][tc4 + 0] = f2bf(v.x); t[k][tc4 + 1] = f2bf(v.y);
    t[k][tc4 + 2] = f2bf(v.z); t[k][tc4 + 3] = f2bf(v.w);
  }
  __syncthreads();
#pragma unroll
  for (int i = 0; i < 4; ++i) {
    const int n = tr + i * 16;
    short4 o;
    o.x = t[tc4 + 0][n]; o.y = t[tc4 + 1][n];
    o.z = t[tc4 + 2][n]; o.w = t[tc4 + 3][n];
    *(short4*)(dst + (size_t)(n0 + n) * K + k0 + tc4) = o;
  }
}

// ------------ bf16 MFMA GEMM, 256xBN tile, 8 waves, double-buffered -------------
// Waves 2M x 4N; per-wave output 128 x (BN/4). Per K-tile (BK=64): STAGE of the
// NEXT tile is issued FIRST (prefetch hides under compute), then 4 quadrant MFMA
// clusters (setprio-wrapped), then ONE barrier (compiler drains vmcnt there,
// after ~500cy of compute latency-hiding). XOR-chunk LDS swizzle (conflict-free,
// verified on 128^2 version) + bijective XCD blockIdx swizzle.
template <int BN_, int OUT, bool RELU>
__global__ __launch_bounds__(512, 2) void mfma_gemm2(
    const short* __restrict__ A, const short* __restrict__ BT,
    const float* __restrict__ bias, const float* __restrict__ res,
    void* __restrict__ Cout, int N, int K) {
  constexpr int BM = 256;
  constexpr int NJ = BN_ / 64;   // n-frags per wave (4 or 2); also B stage issues
  constexpr int NJ2 = NJ / 2;    // n-frags per quadrant
  __shared__ __align__(16) short As[2][BM * 64];
  __shared__ __align__(16) short Bs[2][BN_ * 64];
  const int tid = threadIdx.x;
  const int w = tid >> 6, lane = tid & 63;
  const int n16 = lane & 15, quad = lane >> 4;
  const int gridN = N / BN_;
  int bid = blockIdx.x;
  const int nwg = gridDim.x;
  if ((nwg & 7) == 0) bid = (bid & 7) * (nwg >> 3) + (bid >> 3);
  const int m0 = (bid / gridN) * BM, n0 = (bid % gridN) * BN_;
  const int wr = (w >> 2) * 128, wc = (w & 3) * (BN_ / 4);

  const short* Ap = A + (size_t)m0 * K;
  const short* Bp = BT + (size_t)n0 * K;

  f32x4 acc[8][NJ];
#pragma unroll
  for (int i = 0; i < 8; ++i)
#pragma unroll
    for (int j = 0; j < NJ; ++j) acc[i][j] = (f32x4)0.f;

  const int srow = tid >> 3;   // 0..63: row within a 64-row staging round
  const int schunk = tid & 7;  // 16B chunk slot

  auto STAGE = [&](int buf, int k0) {
#pragma unroll
    for (int i = 0; i < 4; ++i) {
      const int r = i * 64 + srow;
      __builtin_amdgcn_global_load_lds(
          (gas_t)(const void*)(Ap + (size_t)r * K + k0 + ((schunk ^ (r & 7)) << 3)),
          (las_t)(void*)(As[buf] + (i * 64 + w * 8) * 64), 16, 0, 0);
    }
#pragma unroll
    for (int i = 0; i < NJ; ++i) {
      const int r = i * 64 + srow;
      __builtin_amdgcn_global_load_lds(
          (gas_t)(const void*)(Bp + (size_t)r * K + k0 + ((schunk ^ (r & 7)) << 3)),
          (las_t)(void*)(Bs[buf] + (i * 64 + w * 8) * 64), 16, 0, 0);
    }
  };

  STAGE(0, 0);
  __syncthreads();
  int cur = 0;

  for (int k0 = 0; k0 < K; k0 += 64) {
    if (k0 + 64 < K) STAGE(cur ^ 1, k0 + 64);  // issue-early prefetch
    const short* as_ = As[cur];
    const short* bs_ = Bs[cur];

    bf16x8 bf[NJ][2];
#pragma unroll
    for (int j = 0; j < NJ; ++j) {
      const int n = wc + j * 16 + n16;
#pragma unroll
      for (int kc = 0; kc < 2; ++kc)
        bf[j][kc] =
            *(const bf16x8*)(bs_ + n * 64 + ((((kc << 2) + quad) ^ (n & 7)) << 3));
    }
#pragma unroll
    for (int qm = 0; qm < 2; ++qm) {
      bf16x8 af[4][2];
#pragma unroll
      for (int i = 0; i < 4; ++i) {
        const int m = wr + (qm * 4 + i) * 16 + n16;
#pragma unroll
        for (int kc = 0; kc < 2; ++kc)
          af[i][kc] =
              *(const bf16x8*)(as_ + m * 64 + ((((kc << 2) + quad) ^ (m & 7)) << 3));
      }
#pragma unroll
      for (int qn = 0; qn < 2; ++qn) {
        __builtin_amdgcn_s_setprio(1);
#pragma unroll
        for (int i = 0; i < 4; ++i)
#pragma unroll
          for (int j = 0; j < NJ2; ++j)
#pragma unroll
            for (int kc = 0; kc < 2; ++kc)
              acc[qm * 4 + i][qn * NJ2 + j] =
                  __builtin_amdgcn_mfma_f32_16x16x32_bf16(
                      af[i][kc], bf[qn * NJ2 + j][kc],
                      acc[qm * 4 + i][qn * NJ2 + j], 0, 0, 0);
        __builtin_amdgcn_s_setprio(0);
      }
    }
    __syncthreads();  // single drain per K-tile, after compute
    cur ^= 1;
  }

#pragma unroll
  for (int j = 0; j < NJ; ++j) {
    const int n = n0 + wc + j * 16 + n16;
    const float bv = bias[n];
#pragma unroll
    for (int i = 0; i < 8; ++i) {
#pragma unroll
      for (int r = 0; r < 4; ++r) {
        const int m = m0 + wr + i * 16 + quad * 4 + r;
        float v = acc[i][j][r] + bv;
        if (OUT == 1) {
          ((float*)Cout)[(size_t)m * N + n] = v + res[(size_t)m * N + n];
        } else {
          if (RELU) v = fmaxf(v, 0.f);
          ((short*)Cout)[(size_t)m * N + n] = f2bf(v);
        }
      }
    }
  }
}

// ---------------- MFMA bf16 flash attention, swapped-QK 32x32 structure ---------
__global__ __launch_bounds__(256) void attn_kernel(
    const short* __restrict__ qkv, const float* __restrict__ amaskp,
    short* __restrict__ ctx) {
  // per buffer: K [64 keys][64 d] chunk-swizzled (8KB) | V subtiled [16][4][4][16] (8KB)
  __shared__ __align__(16) short smem[2][8192];

  const int tid = threadIdx.x;
  const int w = tid >> 6;
  const int lane = tid & 63;
  const int l31 = lane & 31;
  const int hi = lane >> 5;
  const int bh = blockIdx.x;
  const int bb = bh >> 4, hh = bh & 15;
  const int qb = gridDim.y - 1 - blockIdx.y;  // heavy causal blocks first
  const int q0 = qb * 128;
  const int qw0 = q0 + w * 32;

  const short* base  = qkv + (size_t)bb * kT * 3072;
  const short* kbase = base + 1024 + hh * 64;
  const short* vbase = base + 2048 + hh * 64;
  const float* amp   = amaskp + bb * kT;

  bf16x8 qf[4];
  {
    const short* qp = base + (size_t)(qw0 + l31) * 3072 + hh * 64 + hi * 8;
#pragma unroll
    for (int mi = 0; mi < 4; ++mi) qf[mi] = *(const bf16x8*)(qp + mi * 16);
  }

  f32x16 O[2];
  O[0] = (f32x16)0.f;
  O[1] = (f32x16)0.f;
  float m_r = -1e30f, l_r = 0.f;

  const int krow = tid >> 3, kch = tid & 7;
  const int vk4 = tid >> 5, vd16 = (tid >> 3) & 3;
  const int vkin = (tid >> 1) & 3, vdh = tid & 1;
  const int wuni = (tid & 192) * 8;

  const unsigned vs0 = (unsigned)(size_t)(las_t)(void*)(&smem[0][4096]);
  const int g = lane >> 4;
  const unsigned vtr =
      vs0 + (unsigned)((g >> 1) * 1024 + (g & 1) * 128 + (lane & 15) * 8);

  auto STAGE = [&](int buf, int k0) {
    short* ks = &smem[buf][0];
    short* vs = &smem[buf][4096];
#pragma unroll
    for (int r2 = 0; r2 < 2; ++r2) {
      const int rr = r2 * 32 + krow;
      __builtin_amdgcn_global_load_lds(
          (gas_t)(const void*)(kbase + (size_t)(k0 + rr) * 3072 +
                               ((kch ^ (rr & 7)) << 3)),
          (las_t)(void*)(ks + r2 * 2048 + wuni), 16, 0, 0);
      const int key = k0 + r2 * 32 + vk4 * 4 + vkin;
      __builtin_amdgcn_global_load_lds(
          (gas_t)(const void*)(vbase + (size_t)key * 3072 + vd16 * 16 + vdh * 8),
          (las_t)(void*)(vs + r2 * 2048 + wuni), 16, 0, 0);
    }
  };

  const int kend = q0 + 128;
  STAGE(0, 0);
  __syncthreads();
  int cur = 0;

  for (int k0 = 0; k0 < kend; k0 += 64) {
    if (k0 + 64 < kend) STAGE(cur ^ 1, k0 + 64);

    if (k0 <= qw0 + 31) {
      const short* ks = &smem[cur][0];

      f32x16 st[2];
      st[0] = (f32x16)0.f;
      st[1] = (f32x16)0.f;
#pragma unroll
      for (int s = 0; s < 2; ++s) {
        const int row = s * 32 + l31;
        const short* kp = ks + row * 64;
#pragma unroll
        for (int mi = 0; mi < 4; ++mi) {
          const bf16x8 kf =
              *(const bf16x8*)(kp + (((2 * mi + hi) ^ (row & 7)) << 3));
          st[s] = __builtin_amdgcn_mfma_f32_32x32x16_bf16(kf, qf[mi], st[s],
                                                          0, 0, 0);
        }
      }

#pragma unroll
      for (int s = 0; s < 2; ++s) {
        const bool pm = (k0 + 32 * s + 31 > qw0);
#pragma unroll
        for (int rq = 0; rq < 4; ++rq) {
          const int kb_ = k0 + 32 * s + 8 * rq + 4 * hi;
          const float4 a4 = *(const float4*)(amp + kb_);
          const float amv0 = (1.f - a4.x) * -10000.f;
          const float amv1 = (1.f - a4.y) * -10000.f;
          const float amv2 = (1.f - a4.z) * -10000.f;
          const float amv3 = (1.f - a4.w) * -10000.f;
          float v0 = st[s][rq * 4 + 0] * 0.125f;
          float v1 = st[s][rq * 4 + 1] * 0.125f;
          float v2 = st[s][rq * 4 + 2] * 0.125f;
          float v3 = st[s][rq * 4 + 3] * 0.125f;
          if (pm) {
            const int q = qw0 + l31;
            if (kb_ + 0 > q) v0 = -10000.f;
            if (kb_ + 1 > q) v1 = -10000.f;
            if (kb_ + 2 > q) v2 = -10000.f;
            if (kb_ + 3 > q) v3 = -10000.f;
          }
          st[s][rq * 4 + 0] = v0 + amv0;
          st[s][rq * 4 + 1] = v1 + amv1;
          st[s][rq * 4 + 2] = v2 + amv2;
          st[s][rq * 4 + 3] = v3 + amv3;
        }
      }

      float mx = st[0][0];
#pragma unroll
      for (int r = 1; r < 16; ++r) mx = fmaxf(mx, st[0][r]);
#pragma unroll
      for (int r = 0; r < 16; ++r) mx = fmaxf(mx, st[1][r]);
      mx = fmaxf(mx, __shfl_xor(mx, 32, 64));
      const float mn = fmaxf(m_r, mx);
      const float al = __expf(m_r - mn);
      m_r = mn;
      float sum = 0.f;
#pragma unroll
      for (int s = 0; s < 2; ++s)
#pragma unroll
        for (int r = 0; r < 16; ++r) {
          const float p = __expf(st[s][r] - mn);
          st[s][r] = p;
          sum += p;
        }
      sum += __shfl_xor(sum, 32, 64);
      l_r = l_r * al + sum;
#pragma unroll
      for (int r = 0; r < 16; ++r) {
        O[0][r] *= al;
        O[1][r] *= al;
      }

      bf16x8 pf[4];
      const bool ishi = (hi != 0);
#pragma unroll
      for (int s = 0; s < 2; ++s) {
#pragma unroll
        for (int hf = 0; hf < 2; ++hf) {
          unsigned wa = cvtpk_bf16(st[s][8 * hf + 0], st[s][8 * hf + 1]);
          unsigned wc = cvtpk_bf16(st[s][8 * hf + 4], st[s][8 * hf + 5]);
          half_swap(wa, wc, ishi);
          unsigned wb = cvtpk_bf16(st[s][8 * hf + 2], st[s][8 * hf + 3]);
          unsigned wd = cvtpk_bf16(st[s][8 * hf + 6], st[s][8 * hf + 7]);
          half_swap(wb, wd, ishi);
          union { unsigned u[4]; bf16x8 h; } f;
          f.u[0] = wa; f.u[1] = wb; f.u[2] = wc; f.u[3] = wd;
          pf[s * 2 + hf] = f.h;
        }
      }

      unsigned long long tv[16];
      const unsigned vb_ = vtr + (unsigned)(cur << 14);
#pragma unroll
      for (int c = 0; c < 4; ++c)
#pragma unroll
        for (int di = 0; di < 2; ++di) {
          asm volatile("ds_read_b64_tr_b16 %0, %1 offset:%2"
                       : "=v"(tv[(c * 2 + di) * 2 + 0])
                       : "v"(vb_), "n"(c * 2048 + di * 256));
          asm volatile("ds_read_b64_tr_b16 %0, %1 offset:%2"
                       : "=v"(tv[(c * 2 + di) * 2 + 1])
                       : "v"(vb_), "n"(c * 2048 + di * 256 + 512));
        }
      asm volatile("s_waitcnt lgkmcnt(0)" ::: "memory");
      __builtin_amdgcn_sched_barrier(0);
#pragma unroll
      for (int c = 0; c < 4; ++c)
#pragma unroll
        for (int di = 0; di < 2; ++di) {
          union { unsigned long long q[2]; bf16x8 h; } vf_;
          vf_.q[0] = tv[(c * 2 + di) * 2 + 0];
          vf_.q[1] = tv[(c * 2 + di) * 2 + 1];
          O[di] = __builtin_amdgcn_mfma_f32_32x32x16_bf16(vf_.h, pf[c], O[di],
                                                          0, 0, 0);
        }
    }

    __syncthreads();
    cur ^= 1;
  }

  const float inv = 1.f / l_r;
  const size_t tok = (size_t)bb * kT + qw0 + l31;
  short* cp = ctx + tok * 1024 + hh * 64 + 4 * hi;
#pragma unroll
  for (int di = 0; di < 2; ++di)
#pragma unroll
    for (int rq = 0; rq < 4; ++rq) {
      short4 o4;
      o4.x = f2bf(O[di][rq * 4 + 0] * inv);
      o4.y = f2bf(O[di][rq * 4 + 1] * inv);
      o4.z = f2bf(O[di][rq * 4 + 2] * inv);
      o4.w = f2bf(O[di][rq * 4 + 3] * inv);
      *(short4*)(cp + di * 32 + rq * 8) = o4;
    }
}

// --------------------------------- launcher -------------------------------------
extern "C" void kernel_launch(void* const* d_in, const int* in_sizes, int n_in,
                              void* d_out, int out_size, void* d_ws, size_t ws_size,
                              hipStream_t stream) {
  const float* emb   = (const float*)d_in[0];
  const float* amask = (const float*)d_in[1];
  const float* ln1w  = (const float*)d_in[2];
  const float* ln1b  = (const float*)d_in[3];
  const float* attnw = (const float*)d_in[4];
  const float* attnb = (const float*)d_in[5];
  const float* projw = (const float*)d_in[6];
  const float* projb = (const float*)d_in[7];
  const float* ln2w  = (const float*)d_in[8];
  const float* ln2b  = (const float*)d_in[9];
  const float* fcw   = (const float*)d_in[10];
  const float* fcb   = (const float*)d_in[11];
  const float* fcpw  = (const float*)d_in[12];
  const float* fcpb  = (const float*)d_in[13];
  const float* lnfw  = (const float*)d_in[14];
  const float* lnfb  = (const float*)d_in[15];
  float* out = (float*)d_out;

  float* h    = (float*)d_ws;                          // 4096x1024 fp32
  short* xb   = (short*)(h + (size_t)kM * kD);         // 4096x1024 bf16
  short* ctxb = xb + (size_t)kM * kD;                  // 4096x1024 bf16
  short* bigb = ctxb + (size_t)kM * kD;                // 4096x4096 bf16 (qkv/ffn)
  short* awT  = bigb + (size_t)kM * kInner;            // 3072x1024
  short* pwT  = awT + (size_t)3072 * 1024;             // 1024x1024
  short* fwT  = pwT + (size_t)1024 * 1024;             // 4096x1024
  short* gwT  = fwT + (size_t)4096 * 1024;             // 1024x4096

  hipMemcpyAsync(h, emb, sizeof(float) * (size_t)kM * kD,
                 hipMemcpyDeviceToDevice, stream);

  const dim3 blk(256);
  const dim3 blk512(512);
  for (int l = 0; l < kL; ++l) {
    convT_kernel<<<3072, blk, 0, stream>>>(
        attnw + (size_t)l * kD * 3072, projw + (size_t)l * kD * kD,
        fcw + (size_t)l * kD * kInner, fcpw + (size_t)l * kInner * kD,
        awT, pwT, fwT, gwT);
    ln_kernel<short><<<kM, blk, 0, stream>>>(h, ln1w + l * kD, ln1b + l * kD, xb);
    // qkv: [4096,3072] = xb[4096,1024] @ awT^T  -> grid 12*16=192
    mfma_gemm2<256, 0, false><<<(3072 / 256) * (kM / 256), blk512, 0, stream>>>(
        xb, awT, attnb + l * 3072, nullptr, bigb, 3072, 1024);
    attn_kernel<<<dim3(kB * kH, kT / 128), blk, 0, stream>>>(bigb, amask, ctxb);
    // proj: [4096,1024] += ctxb @ pwT^T -> grid 8*16=128
    mfma_gemm2<128, 1, false><<<(1024 / 128) * (kM / 256), blk512, 0, stream>>>(
        ctxb, pwT, projb + l * kD, h, h, 1024, 1024);
    ln_kernel<short><<<kM, blk, 0, stream>>>(h, ln2w + l * kD, ln2b + l * kD, xb);
    // fc: [4096,4096] relu -> grid 16*16=256
    mfma_gemm2<256, 0, true><<<(4096 / 256) * (kM / 256), blk512, 0, stream>>>(
        xb, fwT, fcb + l * kInner, nullptr, bigb, 4096, 1024);
    // fcp: [4096,1024] += bigb @ gwT^T (K=4096) -> grid 8*16=128
    mfma_gemm2<128, 1, false><<<(1024 / 128) * (kM / 256), blk512, 0, stream>>>(
        bigb, gwT, fcpb + l * kD, h, h, 1024, 4096);
  }
  ln_kernel<float><<<kM, blk, 0, stream>>>(h, lnfw, lnfb, out);
}

// Round 4
// 2392.315 us; speedup vs baseline: 1.0784x; 1.0784x over previous
//
#include <hip/hip_runtime.h>
#include <math.h>

namespace {
constexpr int kB = 2;
constexpr int kT = 2048;
constexpr int kD = 1024;
constexpr int kH = 16;
constexpr int kL = 8;
constexpr int kInner = 4096;
constexpr int kM = kB * kT;  // 4096 token rows
constexpr float kEps = 1e-5f;
}

typedef __attribute__((ext_vector_type(8))) short bf16x8;
typedef __attribute__((ext_vector_type(4))) float f32x4;
typedef __attribute__((ext_vector_type(16))) float f32x16;

typedef const __attribute__((address_space(1))) void* gas_t;
typedef __attribute__((address_space(3))) void* las_t;

__device__ __forceinline__ short f2bf(float f) {
  union { float f; unsigned u; } v{f};
  unsigned r = (v.u + 0x7FFF + ((v.u >> 16) & 1)) >> 16;
  return (short)r;
}

__device__ __forceinline__ unsigned cvtpk_bf16(float lo, float hi) {
  unsigned r;
  asm("v_cvt_pk_bf16_f32 %0, %1, %2" : "=v"(r) : "v"(lo), "v"(hi));
  return r;
}

__device__ __forceinline__ void half_swap(unsigned& a, unsigned& b, bool ishi) {
  const unsigned sel = ishi ? a : b;
  const unsigned got = (unsigned)__shfl_xor((int)sel, 32, 64);
  a = ishi ? got : a;
  b = ishi ? b : got;
}

// ---------------- LayerNorm: one 256-thread block per row of 1024 ----------------
template <typename OT>
__global__ __launch_bounds__(256) void ln_kernel(
    const float* __restrict__ in, const float* __restrict__ w,
    const float* __restrict__ b, OT* __restrict__ out) {
  const int row = blockIdx.x;
  const int tid = threadIdx.x;
  const float4 v = ((const float4*)(in + (size_t)row * kD))[tid];
  float sum = v.x + v.y + v.z + v.w;
  float sq = v.x * v.x + v.y * v.y + v.z * v.z + v.w * v.w;
#pragma unroll
  for (int off = 32; off > 0; off >>= 1) {
    sum += __shfl_down(sum, off);
    sq += __shfl_down(sq, off);
  }
  __shared__ float s1[4], s2[4];
  const int wave = tid >> 6, lane = tid & 63;
  if (lane == 0) { s1[wave] = sum; s2[wave] = sq; }
  __syncthreads();
  const float ts = s1[0] + s1[1] + s1[2] + s1[3];
  const float tq = s2[0] + s2[1] + s2[2] + s2[3];
  const float mean = ts * (1.0f / kD);
  const float var = tq * (1.0f / kD) - mean * mean;
  const float rs = rsqrtf(var + kEps);
  const float4 w4 = ((const float4*)w)[tid];
  const float4 b4 = ((const float4*)b)[tid];
  float4 o;
  o.x = (v.x - mean) * rs * w4.x + b4.x;
  o.y = (v.y - mean) * rs * w4.y + b4.y;
  o.z = (v.z - mean) * rs * w4.z + b4.z;
  o.w = (v.w - mean) * rs * w4.w + b4.w;
  if constexpr (sizeof(OT) == 4) {
    ((float4*)(out + (size_t)row * kD))[tid] = o;
  } else {
    short4 s4;
    s4.x = f2bf(o.x); s4.y = f2bf(o.y); s4.z = f2bf(o.z); s4.w = f2bf(o.w);
    ((short4*)(out + (size_t)row * kD))[tid] = s4;
  }
}

// ------------- per-layer weight convert+transpose: fp32 [K,N] -> bf16 [N,K] -----
__global__ __launch_bounds__(256) void convT_kernel(
    const float* __restrict__ aw, const float* __restrict__ pw,
    const float* __restrict__ fw, const float* __restrict__ gw,
    short* __restrict__ awT, short* __restrict__ pwT,
    short* __restrict__ fwT, short* __restrict__ gwT) {
  __shared__ short t[64][66];
  int b = blockIdx.x;
  const float* src; short* dst; int K, N, tk, tn;
  if (b < 768)       { src = aw; dst = awT; K = 1024; N = 3072; tk = b / 48; tn = b % 48; }
  else if (b < 1024) { b -= 768;  src = pw; dst = pwT; K = 1024; N = 1024; tk = b / 16; tn = b % 16; }
  else if (b < 2048) { b -= 1024; src = fw; dst = fwT; K = 1024; N = 4096; tk = b / 64; tn = b % 64; }
  else               { b -= 2048; src = gw; dst = gwT; K = 4096; N = 1024; tk = b / 16; tn = b % 16; }
  const int k0 = tk * 64, n0 = tn * 64;
  const int tr = threadIdx.x >> 4, tc4 = (threadIdx.x & 15) << 2;
#pragma unroll
  for (int i = 0; i < 4; ++i) {
    const int k = tr + i * 16;
    const float4 v = *(const float4*)(src + (size_t)(k0 + k) * N + n0 + tc4);
    t[k][tc4 + 0] = f2bf(v.x); t[k][tc4 + 1] = f2bf(v.y);
    t[k][tc4 + 2] = f2bf(v.z); t[k][tc4 + 3] = f2bf(v.w);
  }
  __syncthreads();
#pragma unroll
  for (int i = 0; i < 4; ++i) {
    const int n = tr + i * 16;
    short4 o;
    o.x = t[tc4 + 0][n]; o.y = t[tc4 + 1][n];
    o.z = t[tc4 + 2][n]; o.w = t[tc4 + 3][n];
    *(short4*)(dst + (size_t)(n0 + n) * K + k0 + tc4) = o;
  }
}

// ------ bf16 MFMA GEMM, 128x128 tile, 4 waves (2x2), double-buffered ------------
// Per-wave output 64x64 (32 MFMA : 16 ds_read_b128 per K-step, ratio 2.0).
// Per K-step: issue next-tile STAGE first (latency hides under compute), ds_read
// frags, setprio-wrapped 32-MFMA cluster, ONE barrier. 64 KiB LDS -> 2 blocks/CU
// resident (m114 inter-block overlap). Grids: qkv 768 / proj 256 / fc 1024 /
// fcp 256 -- every GEMM fills all 256 CUs (R3's 128-block grids left half the
// chip idle). XOR-chunk LDS swizzle + bijective XCD swizzle (grids %8==0).
template <int OUT, bool RELU>
__global__ __launch_bounds__(256, 2) void mfma_gemm3(
    const short* __restrict__ A, const short* __restrict__ BT,
    const float* __restrict__ bias, const float* __restrict__ res,
    void* __restrict__ Cout, int N, int K) {
  __shared__ __align__(16) short As[2][128 * 64];
  __shared__ __align__(16) short Bs[2][128 * 64];
  const int tid = threadIdx.x;
  const int w = tid >> 6, lane = tid & 63;
  const int n16 = lane & 15, quad = lane >> 4;
  const int gridN = N >> 7;
  int bid = blockIdx.x;
  const int nwg = gridDim.x;
  bid = (bid & 7) * (nwg >> 3) + (bid >> 3);  // XCD swizzle (all grids %8==0)
  const int m0 = (bid / gridN) * 128, n0 = (bid % gridN) * 128;
  const int wr = (w >> 1) * 64, wc = (w & 1) * 64;

  const short* Ap = A + (size_t)m0 * K;
  const short* Bp = BT + (size_t)n0 * K;

  f32x4 acc[4][4];
#pragma unroll
  for (int i = 0; i < 4; ++i)
#pragma unroll
    for (int j = 0; j < 4; ++j) acc[i][j] = (f32x4)0.f;

  const int srow = tid >> 3;   // 0..31: row within a 32-row staging round
  const int schunk = tid & 7;  // 16B chunk slot

  auto STAGE = [&](int buf, int k0) {
#pragma unroll
    for (int i = 0; i < 4; ++i) {
      const int r = i * 32 + srow;
      const int cs = (schunk ^ (r & 7)) << 3;
      __builtin_amdgcn_global_load_lds(
          (gas_t)(const void*)(Ap + (size_t)r * K + k0 + cs),
          (las_t)(void*)(As[buf] + (i * 32 + w * 8) * 64), 16, 0, 0);
      __builtin_amdgcn_global_load_lds(
          (gas_t)(const void*)(Bp + (size_t)r * K + k0 + cs),
          (las_t)(void*)(Bs[buf] + (i * 32 + w * 8) * 64), 16, 0, 0);
    }
  };

  STAGE(0, 0);
  __syncthreads();
  int cur = 0;

  for (int k0 = 0; k0 < K; k0 += 64) {
    if (k0 + 64 < K) STAGE(cur ^ 1, k0 + 64);  // issue-early prefetch
    const short* as_ = As[cur];
    const short* bs_ = Bs[cur];

    bf16x8 af[4][2], bf[4][2];
#pragma unroll
    for (int i = 0; i < 4; ++i) {
      const int m = wr + i * 16 + n16;
      const int n = wc + i * 16 + n16;
#pragma unroll
      for (int kc = 0; kc < 2; ++kc) {
        af[i][kc] =
            *(const bf16x8*)(as_ + m * 64 + ((((kc << 2) + quad) ^ (m & 7)) << 3));
        bf[i][kc] =
            *(const bf16x8*)(bs_ + n * 64 + ((((kc << 2) + quad) ^ (n & 7)) << 3));
      }
    }
    __builtin_amdgcn_s_setprio(1);
#pragma unroll
    for (int i = 0; i < 4; ++i)
#pragma unroll
      for (int j = 0; j < 4; ++j)
#pragma unroll
        for (int kc = 0; kc < 2; ++kc)
          acc[i][j] = __builtin_amdgcn_mfma_f32_16x16x32_bf16(af[i][kc], bf[j][kc],
                                                              acc[i][j], 0, 0, 0);
    __builtin_amdgcn_s_setprio(0);
    __syncthreads();  // single drain per K-step, after compute
    cur ^= 1;
  }

#pragma unroll
  for (int j = 0; j < 4; ++j) {
    const int n = n0 + wc + j * 16 + n16;
    const float bv = bias[n];
#pragma unroll
    for (int i = 0; i < 4; ++i) {
#pragma unroll
      for (int r = 0; r < 4; ++r) {
        const int m = m0 + wr + i * 16 + quad * 4 + r;
        float v = acc[i][j][r] + bv;
        if (OUT == 1) {
          ((float*)Cout)[(size_t)m * N + n] = v + res[(size_t)m * N + n];
        } else {
          if (RELU) v = fmaxf(v, 0.f);
          ((short*)Cout)[(size_t)m * N + n] = f2bf(v);
        }
      }
    }
  }
}

// ---------------- MFMA bf16 flash attention, swapped-QK 32x32 structure ---------
__global__ __launch_bounds__(256) void attn_kernel(
    const short* __restrict__ qkv, const float* __restrict__ amaskp,
    short* __restrict__ ctx) {
  // per buffer: K [64 keys][64 d] chunk-swizzled (8KB) | V subtiled [16][4][4][16] (8KB)
  __shared__ __align__(16) short smem[2][8192];

  const int tid = threadIdx.x;
  const int w = tid >> 6;
  const int lane = tid & 63;
  const int l31 = lane & 31;
  const int hi = lane >> 5;
  const int bh = blockIdx.x;
  const int bb = bh >> 4, hh = bh & 15;
  const int qb = gridDim.y - 1 - blockIdx.y;  // heavy causal blocks first
  const int q0 = qb * 128;
  const int qw0 = q0 + w * 32;

  const short* base  = qkv + (size_t)bb * kT * 3072;
  const short* kbase = base + 1024 + hh * 64;
  const short* vbase = base + 2048 + hh * 64;
  const float* amp   = amaskp + bb * kT;

  bf16x8 qf[4];
  {
    const short* qp = base + (size_t)(qw0 + l31) * 3072 + hh * 64 + hi * 8;
#pragma unroll
    for (int mi = 0; mi < 4; ++mi) qf[mi] = *(const bf16x8*)(qp + mi * 16);
  }

  f32x16 O[2];
  O[0] = (f32x16)0.f;
  O[1] = (f32x16)0.f;
  float m_r = -1e30f, l_r = 0.f;

  const int krow = tid >> 3, kch = tid & 7;
  const int vk4 = tid >> 5, vd16 = (tid >> 3) & 3;
  const int vkin = (tid >> 1) & 3, vdh = tid & 1;
  const int wuni = (tid & 192) * 8;

  const unsigned vs0 = (unsigned)(size_t)(las_t)(void*)(&smem[0][4096]);
  const int g = lane >> 4;
  const unsigned vtr =
      vs0 + (unsigned)((g >> 1) * 1024 + (g & 1) * 128 + (lane & 15) * 8);

  auto STAGE = [&](int buf, int k0) {
    short* ks = &smem[buf][0];
    short* vs = &smem[buf][4096];
#pragma unroll
    for (int r2 = 0; r2 < 2; ++r2) {
      const int rr = r2 * 32 + krow;
      __builtin_amdgcn_global_load_lds(
          (gas_t)(const void*)(kbase + (size_t)(k0 + rr) * 3072 +
                               ((kch ^ (rr & 7)) << 3)),
          (las_t)(void*)(ks + r2 * 2048 + wuni), 16, 0, 0);
      const int key = k0 + r2 * 32 + vk4 * 4 + vkin;
      __builtin_amdgcn_global_load_lds(
          (gas_t)(const void*)(vbase + (size_t)key * 3072 + vd16 * 16 + vdh * 8),
          (las_t)(void*)(vs + r2 * 2048 + wuni), 16, 0, 0);
    }
  };

  const int kend = q0 + 128;
  STAGE(0, 0);
  __syncthreads();
  int cur = 0;

  for (int k0 = 0; k0 < kend; k0 += 64) {
    if (k0 + 64 < kend) STAGE(cur ^ 1, k0 + 64);

    if (k0 <= qw0 + 31) {
      const short* ks = &smem[cur][0];

      f32x16 st[2];
      st[0] = (f32x16)0.f;
      st[1] = (f32x16)0.f;
#pragma unroll
      for (int s = 0; s < 2; ++s) {
        const int row = s * 32 + l31;
        const short* kp = ks + row * 64;
#pragma unroll
        for (int mi = 0; mi < 4; ++mi) {
          const bf16x8 kf =
              *(const bf16x8*)(kp + (((2 * mi + hi) ^ (row & 7)) << 3));
          st[s] = __builtin_amdgcn_mfma_f32_32x32x16_bf16(kf, qf[mi], st[s],
                                                          0, 0, 0);
        }
      }

#pragma unroll
      for (int s = 0; s < 2; ++s) {
        const bool pm = (k0 + 32 * s + 31 > qw0);
#pragma unroll
        for (int rq = 0; rq < 4; ++rq) {
          const int kb_ = k0 + 32 * s + 8 * rq + 4 * hi;
          const float4 a4 = *(const float4*)(amp + kb_);
          const float amv0 = (1.f - a4.x) * -10000.f;
          const float amv1 = (1.f - a4.y) * -10000.f;
          const float amv2 = (1.f - a4.z) * -10000.f;
          const float amv3 = (1.f - a4.w) * -10000.f;
          float v0 = st[s][rq * 4 + 0] * 0.125f;
          float v1 = st[s][rq * 4 + 1] * 0.125f;
          float v2 = st[s][rq * 4 + 2] * 0.125f;
          float v3 = st[s][rq * 4 + 3] * 0.125f;
          if (pm) {
            const int q = qw0 + l31;
            if (kb_ + 0 > q) v0 = -10000.f;
            if (kb_ + 1 > q) v1 = -10000.f;
            if (kb_ + 2 > q) v2 = -10000.f;
            if (kb_ + 3 > q) v3 = -10000.f;
          }
          st[s][rq * 4 + 0] = v0 + amv0;
          st[s][rq * 4 + 1] = v1 + amv1;
          st[s][rq * 4 + 2] = v2 + amv2;
          st[s][rq * 4 + 3] = v3 + amv3;
        }
      }

      float mx = st[0][0];
#pragma unroll
      for (int r = 1; r < 16; ++r) mx = fmaxf(mx, st[0][r]);
#pragma unroll
      for (int r = 0; r < 16; ++r) mx = fmaxf(mx, st[1][r]);
      mx = fmaxf(mx, __shfl_xor(mx, 32, 64));
      const float mn = fmaxf(m_r, mx);
      const float al = __expf(m_r - mn);
      m_r = mn;
      float sum = 0.f;
#pragma unroll
      for (int s = 0; s < 2; ++s)
#pragma unroll
        for (int r = 0; r < 16; ++r) {
          const float p = __expf(st[s][r] - mn);
          st[s][r] = p;
          sum += p;
        }
      sum += __shfl_xor(sum, 32, 64);
      l_r = l_r * al + sum;
#pragma unroll
      for (int r = 0; r < 16; ++r) {
        O[0][r] *= al;
        O[1][r] *= al;
      }

      bf16x8 pf[4];
      const bool ishi = (hi != 0);
#pragma unroll
      for (int s = 0; s < 2; ++s) {
#pragma unroll
        for (int hf = 0; hf < 2; ++hf) {
          unsigned wa = cvtpk_bf16(st[s][8 * hf + 0], st[s][8 * hf + 1]);
          unsigned wc = cvtpk_bf16(st[s][8 * hf + 4], st[s][8 * hf + 5]);
          half_swap(wa, wc, ishi);
          unsigned wb = cvtpk_bf16(st[s][8 * hf + 2], st[s][8 * hf + 3]);
          unsigned wd = cvtpk_bf16(st[s][8 * hf + 6], st[s][8 * hf + 7]);
          half_swap(wb, wd, ishi);
          union { unsigned u[4]; bf16x8 h; } f;
          f.u[0] = wa; f.u[1] = wb; f.u[2] = wc; f.u[3] = wd;
          pf[s * 2 + hf] = f.h;
        }
      }

      unsigned long long tv[16];
      const unsigned vb_ = vtr + (unsigned)(cur << 14);
#pragma unroll
      for (int c = 0; c < 4; ++c)
#pragma unroll
        for (int di = 0; di < 2; ++di) {
          asm volatile("ds_read_b64_tr_b16 %0, %1 offset:%2"
                       : "=v"(tv[(c * 2 + di) * 2 + 0])
                       : "v"(vb_), "n"(c * 2048 + di * 256));
          asm volatile("ds_read_b64_tr_b16 %0, %1 offset:%2"
                       : "=v"(tv[(c * 2 + di) * 2 + 1])
                       : "v"(vb_), "n"(c * 2048 + di * 256 + 512));
        }
      asm volatile("s_waitcnt lgkmcnt(0)" ::: "memory");
      __builtin_amdgcn_sched_barrier(0);
#pragma unroll
      for (int c = 0; c < 4; ++c)
#pragma unroll
        for (int di = 0; di < 2; ++di) {
          union { unsigned long long q[2]; bf16x8 h; } vf_;
          vf_.q[0] = tv[(c * 2 + di) * 2 + 0];
          vf_.q[1] = tv[(c * 2 + di) * 2 + 1];
          O[di] = __builtin_amdgcn_mfma_f32_32x32x16_bf16(vf_.h, pf[c], O[di],
                                                          0, 0, 0);
        }
    }

    __syncthreads();
    cur ^= 1;
  }

  const float inv = 1.f / l_r;
  const size_t tok = (size_t)bb * kT + qw0 + l31;
  short* cp = ctx + tok * 1024 + hh * 64 + 4 * hi;
#pragma unroll
  for (int di = 0; di < 2; ++di)
#pragma unroll
    for (int rq = 0; rq < 4; ++rq) {
      short4 o4;
      o4.x = f2bf(O[di][rq * 4 + 0] * inv);
      o4.y = f2bf(O[di][rq * 4 + 1] * inv);
      o4.z = f2bf(O[di][rq * 4 + 2] * inv);
      o4.w = f2bf(O[di][rq * 4 + 3] * inv);
      *(short4*)(cp + di * 32 + rq * 8) = o4;
    }
}

// --------------------------------- launcher -------------------------------------
extern "C" void kernel_launch(void* const* d_in, const int* in_sizes, int n_in,
                              void* d_out, int out_size, void* d_ws, size_t ws_size,
                              hipStream_t stream) {
  const float* emb   = (const float*)d_in[0];
  const float* amask = (const float*)d_in[1];
  const float* ln1w  = (const float*)d_in[2];
  const float* ln1b  = (const float*)d_in[3];
  const float* attnw = (const float*)d_in[4];
  const float* attnb = (const float*)d_in[5];
  const float* projw = (const float*)d_in[6];
  const float* projb = (const float*)d_in[7];
  const float* ln2w  = (const float*)d_in[8];
  const float* ln2b  = (const float*)d_in[9];
  const float* fcw   = (const float*)d_in[10];
  const float* fcb   = (const float*)d_in[11];
  const float* fcpw  = (const float*)d_in[12];
  const float* fcpb  = (const float*)d_in[13];
  const float* lnfw  = (const float*)d_in[14];
  const float* lnfb  = (const float*)d_in[15];
  float* out = (float*)d_out;

  float* h    = (float*)d_ws;                          // 4096x1024 fp32
  short* xb   = (short*)(h + (size_t)kM * kD);         // 4096x1024 bf16
  short* ctxb = xb + (size_t)kM * kD;                  // 4096x1024 bf16
  short* bigb = ctxb + (size_t)kM * kD;                // 4096x4096 bf16 (qkv/ffn)
  short* awT  = bigb + (size_t)kM * kInner;            // 3072x1024
  short* pwT  = awT + (size_t)3072 * 1024;             // 1024x1024
  short* fwT  = pwT + (size_t)1024 * 1024;             // 4096x1024
  short* gwT  = fwT + (size_t)4096 * 1024;             // 1024x4096

  hipMemcpyAsync(h, emb, sizeof(float) * (size_t)kM * kD,
                 hipMemcpyDeviceToDevice, stream);

  const dim3 blk(256);
  for (int l = 0; l < kL; ++l) {
    convT_kernel<<<3072, blk, 0, stream>>>(
        attnw + (size_t)l * kD * 3072, projw + (size_t)l * kD * kD,
        fcw + (size_t)l * kD * kInner, fcpw + (size_t)l * kInner * kD,
        awT, pwT, fwT, gwT);
    ln_kernel<short><<<kM, blk, 0, stream>>>(h, ln1w + l * kD, ln1b + l * kD, xb);
    // qkv: [4096,3072] -> grid 24*32 = 768
    mfma_gemm3<0, false><<<(3072 / 128) * (kM / 128), blk, 0, stream>>>(
        xb, awT, attnb + l * 3072, nullptr, bigb, 3072, 1024);
    attn_kernel<<<dim3(kB * kH, kT / 128), blk, 0, stream>>>(bigb, amask, ctxb);
    // proj: [4096,1024] += -> grid 8*32 = 256
    mfma_gemm3<1, false><<<(1024 / 128) * (kM / 128), blk, 0, stream>>>(
        ctxb, pwT, projb + l * kD, h, h, 1024, 1024);
    ln_kernel<short><<<kM, blk, 0, stream>>>(h, ln2w + l * kD, ln2b + l * kD, xb);
    // fc: [4096,4096] relu -> grid 32*32 = 1024
    mfma_gemm3<0, true><<<(4096 / 128) * (kM / 128), blk, 0, stream>>>(
        xb, fwT, fcb + l * kInner, nullptr, bigb, 4096, 1024);
    // fcp: [4096,1024] += (K=4096) -> grid 8*32 = 256
    mfma_gemm3<1, false><<<(1024 / 128) * (kM / 128), blk, 0, stream>>>(
        bigb, gwT, fcpb + l * kD, h, h, 1024, 4096);
  }
  ln_kernel<float><<<kM, blk, 0, stream>>>(h, lnfw, lnfb, out);
}

// Round 5
// 2296.229 us; speedup vs baseline: 1.1235x; 1.0418x over previous
//
#include <hip/hip_runtime.h>
#include <math.h>

namespace {
constexpr int kB = 2;
constexpr int kT = 2048;
constexpr int kD = 1024;
constexpr int kH = 16;
constexpr int kL = 8;
constexpr int kInner = 4096;
constexpr int kM = kB * kT;  // 4096 token rows
constexpr float kEps = 1e-5f;
}

typedef __attribute__((ext_vector_type(8))) short bf16x8;
typedef __attribute__((ext_vector_type(4))) float f32x4;
typedef __attribute__((ext_vector_type(16))) float f32x16;

typedef const __attribute__((address_space(1))) void* gas_t;
typedef __attribute__((address_space(3))) void* las_t;

__device__ __forceinline__ short f2bf(float f) {
  union { float f; unsigned u; } v{f};
  unsigned r = (v.u + 0x7FFF + ((v.u >> 16) & 1)) >> 16;
  return (short)r;
}

__device__ __forceinline__ unsigned cvtpk_bf16(float lo, float hi) {
  unsigned r;
  asm("v_cvt_pk_bf16_f32 %0, %1, %2" : "=v"(r) : "v"(lo), "v"(hi));
  return r;
}

__device__ __forceinline__ void half_swap(unsigned& a, unsigned& b, bool ishi) {
  const unsigned sel = ishi ? a : b;
  const unsigned got = (unsigned)__shfl_xor((int)sel, 32, 64);
  a = ishi ? got : a;
  b = ishi ? b : got;
}

// ---------------- LayerNorm: one 256-thread block per row of 1024 ----------------
template <typename OT>
__global__ __launch_bounds__(256) void ln_kernel(
    const float* __restrict__ in, const float* __restrict__ w,
    const float* __restrict__ b, OT* __restrict__ out) {
  const int row = blockIdx.x;
  const int tid = threadIdx.x;
  const float4 v = ((const float4*)(in + (size_t)row * kD))[tid];
  float sum = v.x + v.y + v.z + v.w;
  float sq = v.x * v.x + v.y * v.y + v.z * v.z + v.w * v.w;
#pragma unroll
  for (int off = 32; off > 0; off >>= 1) {
    sum += __shfl_down(sum, off);
    sq += __shfl_down(sq, off);
  }
  __shared__ float s1[4], s2[4];
  const int wave = tid >> 6, lane = tid & 63;
  if (lane == 0) { s1[wave] = sum; s2[wave] = sq; }
  __syncthreads();
  const float ts = s1[0] + s1[1] + s1[2] + s1[3];
  const float tq = s2[0] + s2[1] + s2[2] + s2[3];
  const float mean = ts * (1.0f / kD);
  const float var = tq * (1.0f / kD) - mean * mean;
  const float rs = rsqrtf(var + kEps);
  const float4 w4 = ((const float4*)w)[tid];
  const float4 b4 = ((const float4*)b)[tid];
  float4 o;
  o.x = (v.x - mean) * rs * w4.x + b4.x;
  o.y = (v.y - mean) * rs * w4.y + b4.y;
  o.z = (v.z - mean) * rs * w4.z + b4.z;
  o.w = (v.w - mean) * rs * w4.w + b4.w;
  if constexpr (sizeof(OT) == 4) {
    ((float4*)(out + (size_t)row * kD))[tid] = o;
  } else {
    short4 s4;
    s4.x = f2bf(o.x); s4.y = f2bf(o.y); s4.z = f2bf(o.z); s4.w = f2bf(o.w);
    ((short4*)(out + (size_t)row * kD))[tid] = s4;
  }
}

// ------------- per-layer weight convert+transpose: fp32 [K,N] -> bf16 [N,K] -----
__global__ __launch_bounds__(256) void convT_kernel(
    const float* __restrict__ aw, const float* __restrict__ pw,
    const float* __restrict__ fw, const float* __restrict__ gw,
    short* __restrict__ awT, short* __restrict__ pwT,
    short* __restrict__ fwT, short* __restrict__ gwT) {
  __shared__ short t[64][66];
  int b = blockIdx.x;
  const float* src; short* dst; int K, N, tk, tn;
  if (b < 768)       { src = aw; dst = awT; K = 1024; N = 3072; tk = b / 48; tn = b % 48; }
  else if (b < 1024) { b -= 768;  src = pw; dst = pwT; K = 1024; N = 1024; tk = b / 16; tn = b % 16; }
  else if (b < 2048) { b -= 1024; src = fw; dst = fwT; K = 1024; N = 4096; tk = b / 64; tn = b % 64; }
  else               { b -= 2048; src = gw; dst = gwT; K = 4096; N = 1024; tk = b / 16; tn = b % 16; }
  const int k0 = tk * 64, n0 = tn * 64;
  const int tr = threadIdx.x >> 4, tc4 = (threadIdx.x & 15) << 2;
#pragma unroll
  for (int i = 0; i < 4; ++i) {
    const int k = tr + i * 16;
    const float4 v = *(const float4*)(src + (size_t)(k0 + k) * N + n0 + tc4);
    t[k][tc4 + 0] = f2bf(v.x); t[k][tc4 + 1] = f2bf(v.y);
    t[k][tc4 + 2] = f2bf(v.z); t[k][tc4 + 3] = f2bf(v.w);
  }
  __syncthreads();
#pragma unroll
  for (int i = 0; i < 4; ++i) {
    const int n = tr + i * 16;
    short4 o;
    o.x = t[tc4 + 0][n]; o.y = t[tc4 + 1][n];
    o.z = t[tc4 + 2][n]; o.w = t[tc4 + 3][n];
    *(short4*)(dst + (size_t)(n0 + n) * K + k0 + tc4) = o;
  }
}

// ------ bf16 MFMA GEMM, 128xBN tile, 4 waves (2x2), SINGLE-buffered (m97) -------
// Per K-step: STAGE(k0); barrier; ds_read frags + MFMA; barrier. The stage-drain
// stall at the first barrier is hidden by 3-6 co-resident blocks/CU (m114
// inter-block overlap; m97's 912 TF beat every explicit-dbuf variant m99-m140).
// LDS: 16 KiB A + BN*64*2 B (32 KiB @BN=128, 24 KiB @BN=64). BN=64 for the
// N=1024 GEMMs (proj/fcp) doubles the grid to 512 blocks -> 2+ blocks/CU
// (R4's 256-block grids had exactly 1 block/CU: zero overlap on fcp's 64-step
// K loop). XOR-chunk LDS swizzle + bijective XCD swizzle (all grids %8==0).
template <int BN_, int OUT, bool RELU>
__global__ __launch_bounds__(256, 4) void mfma_gemm3(
    const short* __restrict__ A, const short* __restrict__ BT,
    const float* __restrict__ bias, const float* __restrict__ res,
    void* __restrict__ Cout, int N, int K) {
  constexpr int NJ = BN_ / 32;  // per-wave n-frags (4 @BN=128, 2 @BN=64)
  __shared__ __align__(16) short As[128 * 64];
  __shared__ __align__(16) short Bs[BN_ * 64];
  const int tid = threadIdx.x;
  const int w = tid >> 6, lane = tid & 63;
  const int n16 = lane & 15, quad = lane >> 4;
  const int gridN = N / BN_;
  int bid = blockIdx.x;
  const int nwg = gridDim.x;
  bid = (bid & 7) * (nwg >> 3) + (bid >> 3);  // XCD swizzle (all grids %8==0)
  const int m0 = (bid / gridN) * 128, n0 = (bid % gridN) * BN_;
  const int wr = (w >> 1) * 64, wc = (w & 1) * (BN_ / 2);

  const short* Ap = A + (size_t)m0 * K;
  const short* Bp = BT + (size_t)n0 * K;

  f32x4 acc[4][NJ];
#pragma unroll
  for (int i = 0; i < 4; ++i)
#pragma unroll
    for (int j = 0; j < NJ; ++j) acc[i][j] = (f32x4)0.f;

  const int srow = tid >> 3;   // 0..31: row within a 32-row staging round
  const int schunk = tid & 7;  // 16B chunk slot

  for (int k0 = 0; k0 < K; k0 += 64) {
#pragma unroll
    for (int i = 0; i < 4; ++i) {
      const int r = i * 32 + srow;
      const int cs = (schunk ^ (r & 7)) << 3;
      __builtin_amdgcn_global_load_lds(
          (gas_t)(const void*)(Ap + (size_t)r * K + k0 + cs),
          (las_t)(void*)(As + (i * 32 + w * 8) * 64), 16, 0, 0);
      if (i < NJ)
        __builtin_amdgcn_global_load_lds(
            (gas_t)(const void*)(Bp + (size_t)r * K + k0 + cs),
            (las_t)(void*)(Bs + (i * 32 + w * 8) * 64), 16, 0, 0);
    }
    __syncthreads();

    bf16x8 af[4][2], bf[NJ][2];
#pragma unroll
    for (int i = 0; i < 4; ++i) {
      const int m = wr + i * 16 + n16;
#pragma unroll
      for (int kc = 0; kc < 2; ++kc)
        af[i][kc] =
            *(const bf16x8*)(As + m * 64 + ((((kc << 2) + quad) ^ (m & 7)) << 3));
    }
#pragma unroll
    for (int j = 0; j < NJ; ++j) {
      const int n = wc + j * 16 + n16;
#pragma unroll
      for (int kc = 0; kc < 2; ++kc)
        bf[j][kc] =
            *(const bf16x8*)(Bs + n * 64 + ((((kc << 2) + quad) ^ (n & 7)) << 3));
    }
#pragma unroll
    for (int i = 0; i < 4; ++i)
#pragma unroll
      for (int j = 0; j < NJ; ++j)
#pragma unroll
        for (int kc = 0; kc < 2; ++kc)
          acc[i][j] = __builtin_amdgcn_mfma_f32_16x16x32_bf16(af[i][kc], bf[j][kc],
                                                              acc[i][j], 0, 0, 0);
    __syncthreads();
  }

#pragma unroll
  for (int j = 0; j < NJ; ++j) {
    const int n = n0 + wc + j * 16 + n16;
    const float bv = bias[n];
#pragma unroll
    for (int i = 0; i < 4; ++i) {
#pragma unroll
      for (int r = 0; r < 4; ++r) {
        const int m = m0 + wr + i * 16 + quad * 4 + r;
        float v = acc[i][j][r] + bv;
        if (OUT == 1) {
          ((float*)Cout)[(size_t)m * N + n] = v + res[(size_t)m * N + n];
        } else {
          if (RELU) v = fmaxf(v, 0.f);
          ((short*)Cout)[(size_t)m * N + n] = f2bf(v);
        }
      }
    }
  }
}

// ---------------- MFMA bf16 flash attention, swapped-QK 32x32 structure ---------
__global__ __launch_bounds__(256) void attn_kernel(
    const short* __restrict__ qkv, const float* __restrict__ amaskp,
    short* __restrict__ ctx) {
  // per buffer: K [64 keys][64 d] chunk-swizzled (8KB) | V subtiled [16][4][4][16] (8KB)
  __shared__ __align__(16) short smem[2][8192];

  const int tid = threadIdx.x;
  const int w = tid >> 6;
  const int lane = tid & 63;
  const int l31 = lane & 31;
  const int hi = lane >> 5;
  const int bh = blockIdx.x;
  const int bb = bh >> 4, hh = bh & 15;
  const int qb = gridDim.y - 1 - blockIdx.y;  // heavy causal blocks first
  const int q0 = qb * 128;
  const int qw0 = q0 + w * 32;

  const short* base  = qkv + (size_t)bb * kT * 3072;
  const short* kbase = base + 1024 + hh * 64;
  const short* vbase = base + 2048 + hh * 64;
  const float* amp   = amaskp + bb * kT;

  bf16x8 qf[4];
  {
    const short* qp = base + (size_t)(qw0 + l31) * 3072 + hh * 64 + hi * 8;
#pragma unroll
    for (int mi = 0; mi < 4; ++mi) qf[mi] = *(const bf16x8*)(qp + mi * 16);
  }

  f32x16 O[2];
  O[0] = (f32x16)0.f;
  O[1] = (f32x16)0.f;
  float m_r = -1e30f, l_r = 0.f;

  const int krow = tid >> 3, kch = tid & 7;
  const int vk4 = tid >> 5, vd16 = (tid >> 3) & 3;
  const int vkin = (tid >> 1) & 3, vdh = tid & 1;
  const int wuni = (tid & 192) * 8;

  const unsigned vs0 = (unsigned)(size_t)(las_t)(void*)(&smem[0][4096]);
  const int g = lane >> 4;
  const unsigned vtr =
      vs0 + (unsigned)((g >> 1) * 1024 + (g & 1) * 128 + (lane & 15) * 8);

  auto STAGE = [&](int buf, int k0) {
    short* ks = &smem[buf][0];
    short* vs = &smem[buf][4096];
#pragma unroll
    for (int r2 = 0; r2 < 2; ++r2) {
      const int rr = r2 * 32 + krow;
      __builtin_amdgcn_global_load_lds(
          (gas_t)(const void*)(kbase + (size_t)(k0 + rr) * 3072 +
                               ((kch ^ (rr & 7)) << 3)),
          (las_t)(void*)(ks + r2 * 2048 + wuni), 16, 0, 0);
      const int key = k0 + r2 * 32 + vk4 * 4 + vkin;
      __builtin_amdgcn_global_load_lds(
          (gas_t)(const void*)(vbase + (size_t)key * 3072 + vd16 * 16 + vdh * 8),
          (las_t)(void*)(vs + r2 * 2048 + wuni), 16, 0, 0);
    }
  };

  const int kend = q0 + 128;
  STAGE(0, 0);
  __syncthreads();
  int cur = 0;

  for (int k0 = 0; k0 < kend; k0 += 64) {
    if (k0 + 64 < kend) STAGE(cur ^ 1, k0 + 64);

    if (k0 <= qw0 + 31) {
      const short* ks = &smem[cur][0];

      f32x16 st[2];
      st[0] = (f32x16)0.f;
      st[1] = (f32x16)0.f;
#pragma unroll
      for (int s = 0; s < 2; ++s) {
        const int row = s * 32 + l31;
        const short* kp = ks + row * 64;
#pragma unroll
        for (int mi = 0; mi < 4; ++mi) {
          const bf16x8 kf =
              *(const bf16x8*)(kp + (((2 * mi + hi) ^ (row & 7)) << 3));
          st[s] = __builtin_amdgcn_mfma_f32_32x32x16_bf16(kf, qf[mi], st[s],
                                                          0, 0, 0);
        }
      }

#pragma unroll
      for (int s = 0; s < 2; ++s) {
        const bool pm = (k0 + 32 * s + 31 > qw0);
#pragma unroll
        for (int rq = 0; rq < 4; ++rq) {
          const int kb_ = k0 + 32 * s + 8 * rq + 4 * hi;
          const float4 a4 = *(const float4*)(amp + kb_);
          const float amv0 = (1.f - a4.x) * -10000.f;
          const float amv1 = (1.f - a4.y) * -10000.f;
          const float amv2 = (1.f - a4.z) * -10000.f;
          const float amv3 = (1.f - a4.w) * -10000.f;
          float v0 = st[s][rq * 4 + 0] * 0.125f;
          float v1 = st[s][rq * 4 + 1] * 0.125f;
          float v2 = st[s][rq * 4 + 2] * 0.125f;
          float v3 = st[s][rq * 4 + 3] * 0.125f;
          if (pm) {
            const int q = qw0 + l31;
            if (kb_ + 0 > q) v0 = -10000.f;
            if (kb_ + 1 > q) v1 = -10000.f;
            if (kb_ + 2 > q) v2 = -10000.f;
            if (kb_ + 3 > q) v3 = -10000.f;
          }
          st[s][rq * 4 + 0] = v0 + amv0;
          st[s][rq * 4 + 1] = v1 + amv1;
          st[s][rq * 4 + 2] = v2 + amv2;
          st[s][rq * 4 + 3] = v3 + amv3;
        }
      }

      float mx = st[0][0];
#pragma unroll
      for (int r = 1; r < 16; ++r) mx = fmaxf(mx, st[0][r]);
#pragma unroll
      for (int r = 0; r < 16; ++r) mx = fmaxf(mx, st[1][r]);
      mx = fmaxf(mx, __shfl_xor(mx, 32, 64));
      // T13 defer-max: skip the O-wide rescale while the running max still
      // bounds P by e^8 (bf16/f32 accum headroom; HK THR=8, m239 refcheck'd)
      if (!__all(mx <= m_r + 8.f)) {
        const float mn = fmaxf(m_r, mx);
        const float al = __expf(m_r - mn);
        m_r = mn;
        l_r *= al;
#pragma unroll
        for (int r = 0; r < 16; ++r) {
          O[0][r] *= al;
          O[1][r] *= al;
        }
      }
      float sum = 0.f;
#pragma unroll
      for (int s = 0; s < 2; ++s)
#pragma unroll
        for (int r = 0; r < 16; ++r) {
          const float p = __expf(st[s][r] - m_r);
          st[s][r] = p;
          sum += p;
        }
      sum += __shfl_xor(sum, 32, 64);
      l_r += sum;

      bf16x8 pf[4];
      const bool ishi = (hi != 0);
#pragma unroll
      for (int s = 0; s < 2; ++s) {
#pragma unroll
        for (int hf = 0; hf < 2; ++hf) {
          unsigned wa = cvtpk_bf16(st[s][8 * hf + 0], st[s][8 * hf + 1]);
          unsigned wc = cvtpk_bf16(st[s][8 * hf + 4], st[s][8 * hf + 5]);
          half_swap(wa, wc, ishi);
          unsigned wb = cvtpk_bf16(st[s][8 * hf + 2], st[s][8 * hf + 3]);
          unsigned wd = cvtpk_bf16(st[s][8 * hf + 6], st[s][8 * hf + 7]);
          half_swap(wb, wd, ishi);
          union { unsigned u[4]; bf16x8 h; } f;
          f.u[0] = wa; f.u[1] = wb; f.u[2] = wc; f.u[3] = wd;
          pf[s * 2 + hf] = f.h;
        }
      }

      unsigned long long tv[16];
      const unsigned vb_ = vtr + (unsigned)(cur << 14);
#pragma unroll
      for (int c = 0; c < 4; ++c)
#pragma unroll
        for (int di = 0; di < 2; ++di) {
          asm volatile("ds_read_b64_tr_b16 %0, %1 offset:%2"
                       : "=v"(tv[(c * 2 + di) * 2 + 0])
                       : "v"(vb_), "n"(c * 2048 + di * 256));
          asm volatile("ds_read_b64_tr_b16 %0, %1 offset:%2"
                       : "=v"(tv[(c * 2 + di) * 2 + 1])
                       : "v"(vb_), "n"(c * 2048 + di * 256 + 512));
        }
      asm volatile("s_waitcnt lgkmcnt(0)" ::: "memory");
      __builtin_amdgcn_sched_barrier(0);
#pragma unroll
      for (int c = 0; c < 4; ++c)
#pragma unroll
        for (int di = 0; di < 2; ++di) {
          union { unsigned long long q[2]; bf16x8 h; } vf_;
          vf_.q[0] = tv[(c * 2 + di) * 2 + 0];
          vf_.q[1] = tv[(c * 2 + di) * 2 + 1];
          O[di] = __builtin_amdgcn_mfma_f32_32x32x16_bf16(vf_.h, pf[c], O[di],
                                                          0, 0, 0);
        }
    }

    __syncthreads();
    cur ^= 1;
  }

  const float inv = 1.f / l_r;
  const size_t tok = (size_t)bb * kT + qw0 + l31;
  short* cp = ctx + tok * 1024 + hh * 64 + 4 * hi;
#pragma unroll
  for (int di = 0; di < 2; ++di)
#pragma unroll
    for (int rq = 0; rq < 4; ++rq) {
      short4 o4;
      o4.x = f2bf(O[di][rq * 4 + 0] * inv);
      o4.y = f2bf(O[di][rq * 4 + 1] * inv);
      o4.z = f2bf(O[di][rq * 4 + 2] * inv);
      o4.w = f2bf(O[di][rq * 4 + 3] * inv);
      *(short4*)(cp + di * 32 + rq * 8) = o4;
    }
}

// --------------------------------- launcher -------------------------------------
extern "C" void kernel_launch(void* const* d_in, const int* in_sizes, int n_in,
                              void* d_out, int out_size, void* d_ws, size_t ws_size,
                              hipStream_t stream) {
  const float* emb   = (const float*)d_in[0];
  const float* amask = (const float*)d_in[1];
  const float* ln1w  = (const float*)d_in[2];
  const float* ln1b  = (const float*)d_in[3];
  const float* attnw = (const float*)d_in[4];
  const float* attnb = (const float*)d_in[5];
  const float* projw = (const float*)d_in[6];
  const float* projb = (const float*)d_in[7];
  const float* ln2w  = (const float*)d_in[8];
  const float* ln2b  = (const float*)d_in[9];
  const float* fcw   = (const float*)d_in[10];
  const float* fcb   = (const float*)d_in[11];
  const float* fcpw  = (const float*)d_in[12];
  const float* fcpb  = (const float*)d_in[13];
  const float* lnfw  = (const float*)d_in[14];
  const float* lnfb  = (const float*)d_in[15];
  float* out = (float*)d_out;

  float* h    = (float*)d_ws;                          // 4096x1024 fp32
  short* xb   = (short*)(h + (size_t)kM * kD);         // 4096x1024 bf16
  short* ctxb = xb + (size_t)kM * kD;                  // 4096x1024 bf16
  short* bigb = ctxb + (size_t)kM * kD;                // 4096x4096 bf16 (qkv/ffn)
  short* awT  = bigb + (size_t)kM * kInner;            // 3072x1024
  short* pwT  = awT + (size_t)3072 * 1024;             // 1024x1024
  short* fwT  = pwT + (size_t)1024 * 1024;             // 4096x1024
  short* gwT  = fwT + (size_t)4096 * 1024;             // 1024x4096

  hipMemcpyAsync(h, emb, sizeof(float) * (size_t)kM * kD,
                 hipMemcpyDeviceToDevice, stream);

  const dim3 blk(256);
  for (int l = 0; l < kL; ++l) {
    convT_kernel<<<3072, blk, 0, stream>>>(
        attnw + (size_t)l * kD * 3072, projw + (size_t)l * kD * kD,
        fcw + (size_t)l * kD * kInner, fcpw + (size_t)l * kInner * kD,
        awT, pwT, fwT, gwT);
    ln_kernel<short><<<kM, blk, 0, stream>>>(h, ln1w + l * kD, ln1b + l * kD, xb);
    // qkv: [4096,3072] -> grid 24*32 = 768
    mfma_gemm3<128, 0, false><<<(3072 / 128) * (kM / 128), blk, 0, stream>>>(
        xb, awT, attnb + l * 3072, nullptr, bigb, 3072, 1024);
    attn_kernel<<<dim3(kB * kH, kT / 128), blk, 0, stream>>>(bigb, amask, ctxb);
    // proj: [4096,1024] += -> BN=64, grid 16*32 = 512 (2+ blocks/CU)
    mfma_gemm3<64, 1, false><<<(1024 / 64) * (kM / 128), blk, 0, stream>>>(
        ctxb, pwT, projb + l * kD, h, h, 1024, 1024);
    ln_kernel<short><<<kM, blk, 0, stream>>>(h, ln2w + l * kD, ln2b + l * kD, xb);
    // fc: [4096,4096] relu -> grid 32*32 = 1024
    mfma_gemm3<128, 0, true><<<(4096 / 128) * (kM / 128), blk, 0, stream>>>(
        xb, fwT, fcb + l * kInner, nullptr, bigb, 4096, 1024);
    // fcp: [4096,1024] += (K=4096) -> BN=64, grid 16*32 = 512
    mfma_gemm3<64, 1, false><<<(1024 / 64) * (kM / 128), blk, 0, stream>>>(
        bigb, gwT, fcpb + l * kD, h, h, 1024, 4096);
  }
  ln_kernel<float><<<kM, blk, 0, stream>>>(h, lnfw, lnfb, out);
}

// Round 6
// 2267.758 us; speedup vs baseline: 1.1376x; 1.0126x over previous
//
#include <hip/hip_runtime.h>
#include <math.h>

namespace {
constexpr int kB = 2;
constexpr int kT = 2048;
constexpr int kD = 1024;
constexpr int kH = 16;
constexpr int kL = 8;
constexpr int kInner = 4096;
constexpr int kM = kB * kT;  // 4096 token rows
constexpr float kEps = 1e-5f;
}

typedef __attribute__((ext_vector_type(8))) short bf16x8;
typedef __attribute__((ext_vector_type(4))) float f32x4;
typedef __attribute__((ext_vector_type(16))) float f32x16;

typedef const __attribute__((address_space(1))) void* gas_t;
typedef __attribute__((address_space(3))) void* las_t;

__device__ __forceinline__ short f2bf(float f) {
  union { float f; unsigned u; } v{f};
  unsigned r = (v.u + 0x7FFF + ((v.u >> 16) & 1)) >> 16;
  return (short)r;
}

__device__ __forceinline__ unsigned cvtpk_bf16(float lo, float hi) {
  unsigned r;
  asm("v_cvt_pk_bf16_f32 %0, %1, %2" : "=v"(r) : "v"(lo), "v"(hi));
  return r;
}

__device__ __forceinline__ void half_swap(unsigned& a, unsigned& b, bool ishi) {
  const unsigned sel = ishi ? a : b;
  const unsigned got = (unsigned)__shfl_xor((int)sel, 32, 64);
  a = ishi ? got : a;
  b = ishi ? b : got;
}

// ---------------- LayerNorm: one 256-thread block per row of 1024 ----------------
template <typename OT>
__global__ __launch_bounds__(256) void ln_kernel(
    const float* __restrict__ in, const float* __restrict__ w,
    const float* __restrict__ b, OT* __restrict__ out) {
  const int row = blockIdx.x;
  const int tid = threadIdx.x;
  const float4 v = ((const float4*)(in + (size_t)row * kD))[tid];
  float sum = v.x + v.y + v.z + v.w;
  float sq = v.x * v.x + v.y * v.y + v.z * v.z + v.w * v.w;
#pragma unroll
  for (int off = 32; off > 0; off >>= 1) {
    sum += __shfl_down(sum, off);
    sq += __shfl_down(sq, off);
  }
  __shared__ float s1[4], s2[4];
  const int wave = tid >> 6, lane = tid & 63;
  if (lane == 0) { s1[wave] = sum; s2[wave] = sq; }
  __syncthreads();
  const float ts = s1[0] + s1[1] + s1[2] + s1[3];
  const float tq = s2[0] + s2[1] + s2[2] + s2[3];
  const float mean = ts * (1.0f / kD);
  const float var = tq * (1.0f / kD) - mean * mean;
  const float rs = rsqrtf(var + kEps);
  const float4 w4 = ((const float4*)w)[tid];
  const float4 b4 = ((const float4*)b)[tid];
  float4 o;
  o.x = (v.x - mean) * rs * w4.x + b4.x;
  o.y = (v.y - mean) * rs * w4.y + b4.y;
  o.z = (v.z - mean) * rs * w4.z + b4.z;
  o.w = (v.w - mean) * rs * w4.w + b4.w;
  if constexpr (sizeof(OT) == 4) {
    ((float4*)(out + (size_t)row * kD))[tid] = o;
  } else {
    short4 s4;
    s4.x = f2bf(o.x); s4.y = f2bf(o.y); s4.z = f2bf(o.z); s4.w = f2bf(o.w);
    ((short4*)(out + (size_t)row * kD))[tid] = s4;
  }
}

// ------------- per-layer weight convert+transpose: fp32 [K,N] -> bf16 [N,K] -----
__global__ __launch_bounds__(256) void convT_kernel(
    const float* __restrict__ aw, const float* __restrict__ pw,
    const float* __restrict__ fw, const float* __restrict__ gw,
    short* __restrict__ awT, short* __restrict__ pwT,
    short* __restrict__ fwT, short* __restrict__ gwT) {
  __shared__ short t[64][66];
  int b = blockIdx.x;
  const float* src; short* dst; int K, N, tk, tn;
  if (b < 768)       { src = aw; dst = awT; K = 1024; N = 3072; tk = b / 48; tn = b % 48; }
  else if (b < 1024) { b -= 768;  src = pw; dst = pwT; K = 1024; N = 1024; tk = b / 16; tn = b % 16; }
  else if (b < 2048) { b -= 1024; src = fw; dst = fwT; K = 1024; N = 4096; tk = b / 64; tn = b % 64; }
  else               { b -= 2048; src = gw; dst = gwT; K = 4096; N = 1024; tk = b / 16; tn = b % 16; }
  const int k0 = tk * 64, n0 = tn * 64;
  const int tr = threadIdx.x >> 4, tc4 = (threadIdx.x & 15) << 2;
#pragma unroll
  for (int i = 0; i < 4; ++i) {
    const int k = tr + i * 16;
    const float4 v = *(const float4*)(src + (size_t)(k0 + k) * N + n0 + tc4);
    t[k][tc4 + 0] = f2bf(v.x); t[k][tc4 + 1] = f2bf(v.y);
    t[k][tc4 + 2] = f2bf(v.z); t[k][tc4 + 3] = f2bf(v.w);
  }
  __syncthreads();
#pragma unroll
  for (int i = 0; i < 4; ++i) {
    const int n = tr + i * 16;
    short4 o;
    o.x = t[tc4 + 0][n]; o.y = t[tc4 + 1][n];
    o.z = t[tc4 + 2][n]; o.w = t[tc4 + 3][n];
    *(short4*)(dst + (size_t)(n0 + n) * K + k0 + tc4) = o;
  }
}

// ------ bf16 MFMA GEMM, 128xBN tile, 4 waves (2x2), SINGLE-buffered (m97) -------
// Used for proj/fcp (N=1024): BN=64 -> grid 512 blocks, 2+ blocks/CU.
template <int BN_, int OUT, bool RELU>
__global__ __launch_bounds__(256, 4) void mfma_gemm3(
    const short* __restrict__ A, const short* __restrict__ BT,
    const float* __restrict__ bias, const float* __restrict__ res,
    void* __restrict__ Cout, int N, int K) {
  constexpr int NJ = BN_ / 32;  // per-wave n-frags (4 @BN=128, 2 @BN=64)
  __shared__ __align__(16) short As[128 * 64];
  __shared__ __align__(16) short Bs[BN_ * 64];
  const int tid = threadIdx.x;
  const int w = tid >> 6, lane = tid & 63;
  const int n16 = lane & 15, quad = lane >> 4;
  const int gridN = N / BN_;
  int bid = blockIdx.x;
  const int nwg = gridDim.x;
  bid = (bid & 7) * (nwg >> 3) + (bid >> 3);  // XCD swizzle (all grids %8==0)
  const int m0 = (bid / gridN) * 128, n0 = (bid % gridN) * BN_;
  const int wr = (w >> 1) * 64, wc = (w & 1) * (BN_ / 2);

  const short* Ap = A + (size_t)m0 * K;
  const short* Bp = BT + (size_t)n0 * K;

  f32x4 acc[4][NJ];
#pragma unroll
  for (int i = 0; i < 4; ++i)
#pragma unroll
    for (int j = 0; j < NJ; ++j) acc[i][j] = (f32x4)0.f;

  const int srow = tid >> 3;
  const int schunk = tid & 7;

  for (int k0 = 0; k0 < K; k0 += 64) {
#pragma unroll
    for (int i = 0; i < 4; ++i) {
      const int r = i * 32 + srow;
      const int cs = (schunk ^ (r & 7)) << 3;
      __builtin_amdgcn_global_load_lds(
          (gas_t)(const void*)(Ap + (size_t)r * K + k0 + cs),
          (las_t)(void*)(As + (i * 32 + w * 8) * 64), 16, 0, 0);
      if (i < NJ)
        __builtin_amdgcn_global_load_lds(
            (gas_t)(const void*)(Bp + (size_t)r * K + k0 + cs),
            (las_t)(void*)(Bs + (i * 32 + w * 8) * 64), 16, 0, 0);
    }
    __syncthreads();

    bf16x8 af[4][2], bf[NJ][2];
#pragma unroll
    for (int i = 0; i < 4; ++i) {
      const int m = wr + i * 16 + n16;
#pragma unroll
      for (int kc = 0; kc < 2; ++kc)
        af[i][kc] =
            *(const bf16x8*)(As + m * 64 + ((((kc << 2) + quad) ^ (m & 7)) << 3));
    }
#pragma unroll
    for (int j = 0; j < NJ; ++j) {
      const int n = wc + j * 16 + n16;
#pragma unroll
      for (int kc = 0; kc < 2; ++kc)
        bf[j][kc] =
            *(const bf16x8*)(Bs + n * 64 + ((((kc << 2) + quad) ^ (n & 7)) << 3));
    }
#pragma unroll
    for (int i = 0; i < 4; ++i)
#pragma unroll
      for (int j = 0; j < NJ; ++j)
#pragma unroll
        for (int kc = 0; kc < 2; ++kc)
          acc[i][j] = __builtin_amdgcn_mfma_f32_16x16x32_bf16(af[i][kc], bf[j][kc],
                                                              acc[i][j], 0, 0, 0);
    __syncthreads();
  }

#pragma unroll
  for (int j = 0; j < NJ; ++j) {
    const int n = n0 + wc + j * 16 + n16;
    const float bv = bias[n];
#pragma unroll
    for (int i = 0; i < 4; ++i) {
#pragma unroll
      for (int r = 0; r < 4; ++r) {
        const int m = m0 + wr + i * 16 + quad * 4 + r;
        float v = acc[i][j][r] + bv;
        if (OUT == 1) {
          ((float*)Cout)[(size_t)m * N + n] = v + res[(size_t)m * N + n];
        } else {
          if (RELU) v = fmaxf(v, 0.f);
          ((short*)Cout)[(size_t)m * N + n] = f2bf(v);
        }
      }
    }
  }
}

// ------ bf16 MFMA GEMM, 256x256 tile, 8 waves, 8-phase counted-vmcnt (T3+T4+T5) -
// m201-class schedule in plain HIP. 2 LDS bufs (tile t -> buf t&1), 4 half-tiles
// per K-tile [Ah0,Ah1,Bh0,Bh1], one half staged per phase at lookahead 6.
// Quadrant order (0,0),(1,0),(0,1),(1,1): A-reads end at phase 1, B-reads at
// phase 2 -> every stage targets a region last read >=1 barrier earlier.
// vmcnt(4) once per tile at phase 4 guarantees the NEXT tile fully landed before
// its phase-1 ds_reads (ledger in commit msg); tail tiles gate vmcnt(0).
// Raw s_barrier (no implicit drain) + setprio around each 16-MFMA quadrant.
template <bool RELU>
__global__ __launch_bounds__(512, 2) void mfma_gemm8(
    const short* __restrict__ A, const short* __restrict__ BT,
    const float* __restrict__ bias, short* __restrict__ Cout, int N, int K) {
  __shared__ __align__(16) short As[2][2][128 * 64];  // [buf][half][row*64+k]
  __shared__ __align__(16) short Bs[2][2][128 * 64];
  const int tid = threadIdx.x;
  const int w = tid >> 6, lane = tid & 63;
  const int n16 = lane & 15, quad = lane >> 4;
  const int wm = w >> 2, wn = w & 3;
  const int gridN = N >> 8;
  int bid = blockIdx.x;
  const int nwg = gridDim.x;
  bid = (bid & 7) * (nwg >> 3) + (bid >> 3);  // XCD swizzle (grids %8==0)
  const int m0 = (bid / gridN) * 256, n0 = (bid % gridN) * 256;
  const short* Ap = A + (size_t)m0 * K;
  const short* Bp = BT + (size_t)n0 * K;

  f32x4 acc[8][4];
#pragma unroll
  for (int i = 0; i < 8; ++i)
#pragma unroll
    for (int j = 0; j < 4; ++j) acc[i][j] = (f32x4)0.f;

  const int srow = tid >> 3;   // 0..63
  const int schunk = tid & 7;

  // stage one 128x64 half-tile (2 global_load_lds per thread)
  auto STAGEH = [&](const short* P, short* dst, int half, int kk) {
#pragma unroll
    for (int r = 0; r < 2; ++r) {
      const int row = r * 64 + srow;  // row within half
      __builtin_amdgcn_global_load_lds(
          (gas_t)(const void*)(P + (size_t)(half * 128 + row) * K + kk +
                               ((schunk ^ (row & 7)) << 3)),
          (las_t)(void*)(dst + (r * 64 + w * 8) * 64), 16, 0, 0);
    }
  };

  bf16x8 afA[4][2], afB[4][2], bf[2][2];
  auto LDA = [&](bf16x8 (&af)[4][2], const short* ash, int qm) {
#pragma unroll
    for (int mi = 0; mi < 4; ++mi) {
      const int row = qm * 64 + mi * 16 + n16;
#pragma unroll
      for (int kc = 0; kc < 2; ++kc)
        af[mi][kc] = *(const bf16x8*)(ash + row * 64 +
                                      ((((kc << 2) + quad) ^ (row & 7)) << 3));
    }
  };
  auto LDB = [&](const short* bsw, int qn) {
#pragma unroll
    for (int nj = 0; nj < 2; ++nj) {
      const int row = qn * 32 + nj * 16 + n16;  // within wave's 64-row B slice
#pragma unroll
      for (int kc = 0; kc < 2; ++kc)
        bf[nj][kc] = *(const bf16x8*)(bsw + row * 64 +
                                      ((((kc << 2) + quad) ^ (row & 7)) << 3));
    }
  };

#define MMQ(AF, QM, QN)                                                       \
  {                                                                           \
    __builtin_amdgcn_s_setprio(1);                                            \
    _Pragma("unroll") for (int mi = 0; mi < 4; ++mi)                          \
    _Pragma("unroll") for (int nj = 0; nj < 2; ++nj)                          \
    _Pragma("unroll") for (int kc = 0; kc < 2; ++kc)                          \
        acc[(QM)*4 + mi][(QN)*2 + nj] =                                       \
            __builtin_amdgcn_mfma_f32_16x16x32_bf16(                          \
                AF[mi][kc], bf[nj][kc], acc[(QM)*4 + mi][(QN)*2 + nj],        \
                0, 0, 0);                                                     \
    __builtin_amdgcn_s_setprio(0);                                            \
  }

  const int NT = K >> 6;
  // prologue: H0..H5 = tile0 (A halves, B halves) + tile1 A halves
  STAGEH(Ap, &As[0][0][0], 0, 0);
  STAGEH(Ap, &As[0][1][0], 1, 0);
  STAGEH(Bp, &Bs[0][0][0], 0, 0);
  STAGEH(Bp, &Bs[0][1][0], 1, 0);
  STAGEH(Ap, &As[1][0][0], 0, 64);
  STAGEH(Ap, &As[1][1][0], 1, 64);
  asm volatile("s_waitcnt vmcnt(4)" ::: "memory");  // tile0 landed
  __builtin_amdgcn_s_barrier();

  for (int t = 0; t < NT; ++t) {
    const int buf = t & 1, ob = buf ^ 1;
    const short* aw = &As[buf][wm][0];
    const short* bw = &Bs[buf][wn >> 1][(wn & 1) * 64 * 64];
    const int kn1 = (t + 1) << 6, kn2 = (t + 2) << 6;
    const bool s1 = (t + 1) < NT, s2 = (t + 2) < NT;

    // phase 1: quadrant (0,0)
    LDA(afA, aw, 0);
    LDB(bw, 0);
    if (s1) STAGEH(Bp, &Bs[ob][0][0], 0, kn1);
    __builtin_amdgcn_s_barrier();
    MMQ(afA, 0, 0);
    __builtin_amdgcn_s_barrier();

    // phase 2: quadrant (1,0)
    LDA(afB, aw, 1);
    if (s1) STAGEH(Bp, &Bs[ob][1][0], 1, kn1);
    __builtin_amdgcn_s_barrier();
    MMQ(afB, 1, 0);
    __builtin_amdgcn_s_barrier();

    // phase 3: quadrant (0,1)
    LDB(bw, 1);
    if (s2) STAGEH(Ap, &As[buf][0][0], 0, kn2);
    __builtin_amdgcn_s_barrier();
    MMQ(afA, 0, 1);
    __builtin_amdgcn_s_barrier();

    // phase 4: quadrant (1,1); counted-vmcnt gate for tile t+1
    if (s2) {
      STAGEH(Ap, &As[buf][1][0], 1, kn2);
      asm volatile("s_waitcnt vmcnt(4)" ::: "memory");
    } else {
      asm volatile("s_waitcnt vmcnt(0)" ::: "memory");
    }
    __builtin_amdgcn_s_barrier();
    MMQ(afB, 1, 1);
    __builtin_amdgcn_s_barrier();
  }
#undef MMQ

  // epilogue: bias + optional relu, bf16 store
#pragma unroll
  for (int j = 0; j < 4; ++j) {
    const int n = n0 + wn * 64 + (j >> 1) * 32 + (j & 1) * 16 + n16;
    const float bv = bias[n];
#pragma unroll
    for (int i = 0; i < 8; ++i) {
#pragma unroll
      for (int r = 0; r < 4; ++r) {
        const int m = m0 + wm * 128 + (i >> 2) * 64 + (i & 3) * 16 + quad * 4 + r;
        float v = acc[i][j][r] + bv;
        if (RELU) v = fmaxf(v, 0.f);
        Cout[(size_t)m * N + n] = f2bf(v);
      }
    }
  }
}

// ---------------- MFMA bf16 flash attention, swapped-QK 32x32 structure ---------
__global__ __launch_bounds__(256) void attn_kernel(
    const short* __restrict__ qkv, const float* __restrict__ amaskp,
    short* __restrict__ ctx) {
  // per buffer: K [64 keys][64 d] chunk-swizzled (8KB) | V subtiled [16][4][4][16] (8KB)
  __shared__ __align__(16) short smem[2][8192];

  const int tid = threadIdx.x;
  const int w = tid >> 6;
  const int lane = tid & 63;
  const int l31 = lane & 31;
  const int hi = lane >> 5;
  const int bh = blockIdx.x;
  const int bb = bh >> 4, hh = bh & 15;
  const int qb = gridDim.y - 1 - blockIdx.y;  // heavy causal blocks first
  const int q0 = qb * 128;
  const int qw0 = q0 + w * 32;

  const short* base  = qkv + (size_t)bb * kT * 3072;
  const short* kbase = base + 1024 + hh * 64;
  const short* vbase = base + 2048 + hh * 64;
  const float* amp   = amaskp + bb * kT;

  bf16x8 qf[4];
  {
    const short* qp = base + (size_t)(qw0 + l31) * 3072 + hh * 64 + hi * 8;
#pragma unroll
    for (int mi = 0; mi < 4; ++mi) qf[mi] = *(const bf16x8*)(qp + mi * 16);
  }

  f32x16 O[2];
  O[0] = (f32x16)0.f;
  O[1] = (f32x16)0.f;
  float m_r = -1e30f, l_r = 0.f;

  const int krow = tid >> 3, kch = tid & 7;
  const int vk4 = tid >> 5, vd16 = (tid >> 3) & 3;
  const int vkin = (tid >> 1) & 3, vdh = tid & 1;
  const int wuni = (tid & 192) * 8;

  const unsigned vs0 = (unsigned)(size_t)(las_t)(void*)(&smem[0][4096]);
  const int g = lane >> 4;
  const unsigned vtr =
      vs0 + (unsigned)((g >> 1) * 1024 + (g & 1) * 128 + (lane & 15) * 8);

  auto STAGE = [&](int buf, int k0) {
    short* ks = &smem[buf][0];
    short* vs = &smem[buf][4096];
#pragma unroll
    for (int r2 = 0; r2 < 2; ++r2) {
      const int rr = r2 * 32 + krow;
      __builtin_amdgcn_global_load_lds(
          (gas_t)(const void*)(kbase + (size_t)(k0 + rr) * 3072 +
                               ((kch ^ (rr & 7)) << 3)),
          (las_t)(void*)(ks + r2 * 2048 + wuni), 16, 0, 0);
      const int key = k0 + r2 * 32 + vk4 * 4 + vkin;
      __builtin_amdgcn_global_load_lds(
          (gas_t)(const void*)(vbase + (size_t)key * 3072 + vd16 * 16 + vdh * 8),
          (las_t)(void*)(vs + r2 * 2048 + wuni), 16, 0, 0);
    }
  };

  const int kend = q0 + 128;
  STAGE(0, 0);
  __syncthreads();
  int cur = 0;

  for (int k0 = 0; k0 < kend; k0 += 64) {
    if (k0 + 64 < kend) STAGE(cur ^ 1, k0 + 64);

    if (k0 <= qw0 + 31) {
      const short* ks = &smem[cur][0];

      f32x16 st[2];
      st[0] = (f32x16)0.f;
      st[1] = (f32x16)0.f;
#pragma unroll
      for (int s = 0; s < 2; ++s) {
        const int row = s * 32 + l31;
        const short* kp = ks + row * 64;
#pragma unroll
        for (int mi = 0; mi < 4; ++mi) {
          const bf16x8 kf =
              *(const bf16x8*)(kp + (((2 * mi + hi) ^ (row & 7)) << 3));
          st[s] = __builtin_amdgcn_mfma_f32_32x32x16_bf16(kf, qf[mi], st[s],
                                                          0, 0, 0);
        }
      }

#pragma unroll
      for (int s = 0; s < 2; ++s) {
        const bool pm = (k0 + 32 * s + 31 > qw0);
#pragma unroll
        for (int rq = 0; rq < 4; ++rq) {
          const int kb_ = k0 + 32 * s + 8 * rq + 4 * hi;
          const float4 a4 = *(const float4*)(amp + kb_);
          const float amv0 = (1.f - a4.x) * -10000.f;
          const float amv1 = (1.f - a4.y) * -10000.f;
          const float amv2 = (1.f - a4.z) * -10000.f;
          const float amv3 = (1.f - a4.w) * -10000.f;
          float v0 = st[s][rq * 4 + 0] * 0.125f;
          float v1 = st[s][rq * 4 + 1] * 0.125f;
          float v2 = st[s][rq * 4 + 2] * 0.125f;
          float v3 = st[s][rq * 4 + 3] * 0.125f;
          if (pm) {
            const int q = qw0 + l31;
            if (kb_ + 0 > q) v0 = -10000.f;
            if (kb_ + 1 > q) v1 = -10000.f;
            if (kb_ + 2 > q) v2 = -10000.f;
            if (kb_ + 3 > q) v3 = -10000.f;
          }
          st[s][rq * 4 + 0] = v0 + amv0;
          st[s][rq * 4 + 1] = v1 + amv1;
          st[s][rq * 4 + 2] = v2 + amv2;
          st[s][rq * 4 + 3] = v3 + amv3;
        }
      }

      float mx = st[0][0];
#pragma unroll
      for (int r = 1; r < 16; ++r) mx = fmaxf(mx, st[0][r]);
#pragma unroll
      for (int r = 0; r < 16; ++r) mx = fmaxf(mx, st[1][r]);
      mx = fmaxf(mx, __shfl_xor(mx, 32, 64));
      // T13 defer-max: skip the O-wide rescale while P stays bounded by e^8
      if (!__all(mx <= m_r + 8.f)) {
        const float mn = fmaxf(m_r, mx);
        const float al = __expf(m_r - mn);
        m_r = mn;
        l_r *= al;
#pragma unroll
        for (int r = 0; r < 16; ++r) {
          O[0][r] *= al;
          O[1][r] *= al;
        }
      }
      float sum = 0.f;
#pragma unroll
      for (int s = 0; s < 2; ++s)
#pragma unroll
        for (int r = 0; r < 16; ++r) {
          const float p = __expf(st[s][r] - m_r);
          st[s][r] = p;
          sum += p;
        }
      sum += __shfl_xor(sum, 32, 64);
      l_r += sum;

      bf16x8 pf[4];
      const bool ishi = (hi != 0);
#pragma unroll
      for (int s = 0; s < 2; ++s) {
#pragma unroll
        for (int hf = 0; hf < 2; ++hf) {
          unsigned wa = cvtpk_bf16(st[s][8 * hf + 0], st[s][8 * hf + 1]);
          unsigned wc = cvtpk_bf16(st[s][8 * hf + 4], st[s][8 * hf + 5]);
          half_swap(wa, wc, ishi);
          unsigned wb = cvtpk_bf16(st[s][8 * hf + 2], st[s][8 * hf + 3]);
          unsigned wd = cvtpk_bf16(st[s][8 * hf + 6], st[s][8 * hf + 7]);
          half_swap(wb, wd, ishi);
          union { unsigned u[4]; bf16x8 h; } f;
          f.u[0] = wa; f.u[1] = wb; f.u[2] = wc; f.u[3] = wd;
          pf[s * 2 + hf] = f.h;
        }
      }

      unsigned long long tv[16];
      const unsigned vb_ = vtr + (unsigned)(cur << 14);
#pragma unroll
      for (int c = 0; c < 4; ++c)
#pragma unroll
        for (int di = 0; di < 2; ++di) {
          asm volatile("ds_read_b64_tr_b16 %0, %1 offset:%2"
                       : "=v"(tv[(c * 2 + di) * 2 + 0])
                       : "v"(vb_), "n"(c * 2048 + di * 256));
          asm volatile("ds_read_b64_tr_b16 %0, %1 offset:%2"
                       : "=v"(tv[(c * 2 + di) * 2 + 1])
                       : "v"(vb_), "n"(c * 2048 + di * 256 + 512));
        }
      asm volatile("s_waitcnt lgkmcnt(0)" ::: "memory");
      __builtin_amdgcn_sched_barrier(0);
#pragma unroll
      for (int c = 0; c < 4; ++c)
#pragma unroll
        for (int di = 0; di < 2; ++di) {
          union { unsigned long long q[2]; bf16x8 h; } vf_;
          vf_.q[0] = tv[(c * 2 + di) * 2 + 0];
          vf_.q[1] = tv[(c * 2 + di) * 2 + 1];
          O[di] = __builtin_amdgcn_mfma_f32_32x32x16_bf16(vf_.h, pf[c], O[di],
                                                          0, 0, 0);
        }
    }

    __syncthreads();
    cur ^= 1;
  }

  const float inv = 1.f / l_r;
  const size_t tok = (size_t)bb * kT + qw0 + l31;
  short* cp = ctx + tok * 1024 + hh * 64 + 4 * hi;
#pragma unroll
  for (int di = 0; di < 2; ++di)
#pragma unroll
    for (int rq = 0; rq < 4; ++rq) {
      short4 o4;
      o4.x = f2bf(O[di][rq * 4 + 0] * inv);
      o4.y = f2bf(O[di][rq * 4 + 1] * inv);
      o4.z = f2bf(O[di][rq * 4 + 2] * inv);
      o4.w = f2bf(O[di][rq * 4 + 3] * inv);
      *(short4*)(cp + di * 32 + rq * 8) = o4;
    }
}

// --------------------------------- launcher -------------------------------------
extern "C" void kernel_launch(void* const* d_in, const int* in_sizes, int n_in,
                              void* d_out, int out_size, void* d_ws, size_t ws_size,
                              hipStream_t stream) {
  const float* emb   = (const float*)d_in[0];
  const float* amask = (const float*)d_in[1];
  const float* ln1w  = (const float*)d_in[2];
  const float* ln1b  = (const float*)d_in[3];
  const float* attnw = (const float*)d_in[4];
  const float* attnb = (const float*)d_in[5];
  const float* projw = (const float*)d_in[6];
  const float* projb = (const float*)d_in[7];
  const float* ln2w  = (const float*)d_in[8];
  const float* ln2b  = (const float*)d_in[9];
  const float* fcw   = (const float*)d_in[10];
  const float* fcb   = (const float*)d_in[11];
  const float* fcpw  = (const float*)d_in[12];
  const float* fcpb  = (const float*)d_in[13];
  const float* lnfw  = (const float*)d_in[14];
  const float* lnfb  = (const float*)d_in[15];
  float* out = (float*)d_out;

  float* h    = (float*)d_ws;                          // 4096x1024 fp32
  short* xb   = (short*)(h + (size_t)kM * kD);         // 4096x1024 bf16
  short* ctxb = xb + (size_t)kM * kD;                  // 4096x1024 bf16
  short* bigb = ctxb + (size_t)kM * kD;                // 4096x4096 bf16 (qkv/ffn)
  short* awT  = bigb + (size_t)kM * kInner;            // 3072x1024
  short* pwT  = awT + (size_t)3072 * 1024;             // 1024x1024
  short* fwT  = pwT + (size_t)1024 * 1024;             // 4096x1024
  short* gwT  = fwT + (size_t)4096 * 1024;             // 1024x4096

  hipMemcpyAsync(h, emb, sizeof(float) * (size_t)kM * kD,
                 hipMemcpyDeviceToDevice, stream);

  const dim3 blk(256);
  const dim3 blk512(512);
  for (int l = 0; l < kL; ++l) {
    convT_kernel<<<3072, blk, 0, stream>>>(
        attnw + (size_t)l * kD * 3072, projw + (size_t)l * kD * kD,
        fcw + (size_t)l * kD * kInner, fcpw + (size_t)l * kInner * kD,
        awT, pwT, fwT, gwT);
    ln_kernel<short><<<kM, blk, 0, stream>>>(h, ln1w + l * kD, ln1b + l * kD, xb);
    // qkv: [4096,3072] -> 256^2 8-phase, grid 12*16 = 192
    mfma_gemm8<false><<<(3072 / 256) * (kM / 256), blk512, 0, stream>>>(
        xb, awT, attnb + l * 3072, bigb, 3072, 1024);
    attn_kernel<<<dim3(kB * kH, kT / 128), blk, 0, stream>>>(bigb, amask, ctxb);
    // proj: [4096,1024] += -> BN=64, grid 512 (2+ blocks/CU)
    mfma_gemm3<64, 1, false><<<(1024 / 64) * (kM / 128), blk, 0, stream>>>(
        ctxb, pwT, projb + l * kD, h, h, 1024, 1024);
    ln_kernel<short><<<kM, blk, 0, stream>>>(h, ln2w + l * kD, ln2b + l * kD, xb);
    // fc: [4096,4096] relu -> 256^2 8-phase, grid 16*16 = 256
    mfma_gemm8<true><<<(4096 / 256) * (kM / 256), blk512, 0, stream>>>(
        xb, fwT, fcb + l * kInner, bigb, 4096, 1024);
    // fcp: [4096,1024] += (K=4096) -> BN=64, grid 512
    mfma_gemm3<64, 1, false><<<(1024 / 64) * (kM / 128), blk, 0, stream>>>(
        bigb, gwT, fcpb + l * kD, h, h, 1024, 4096);
  }
  ln_kernel<float><<<kM, blk, 0, stream>>>(h, lnfw, lnfb, out);
}